// Round 1
// baseline (1567.735 us; speedup 1.0000x reference)
//
#include <hip/hip_runtime.h>
#include <stdint.h>

#define EPSV 1e-5f

typedef short short8 __attribute__((ext_vector_type(8)));
typedef float floatx4 __attribute__((ext_vector_type(4)));

static __device__ __forceinline__ ushort f2b(float f) {
    union { float f; uint32_t u; } v; v.f = f;
    return (ushort)((v.u + 0x7FFFu + ((v.u >> 16) & 1u)) >> 16);
}
static __device__ __forceinline__ uint pack2(float a, float b) {
    return (uint)f2b(a) | ((uint)f2b(b) << 16);
}
static __device__ __forceinline__ float b2f(ushort b) {
    union { uint32_t u; float f; } v; v.u = ((uint32_t)b) << 16;
    return v.f;
}

// ---------------- prep kernels ----------------
__global__ void k_prep_w(const float* __restrict__ W, ushort* __restrict__ Wt,
                         int K, int Nc) {
    int i = blockIdx.x * blockDim.x + threadIdx.x;
    if (i >= K * Nc) return;
    int n = i % Nc, k = i / Nc;
    Wt[(size_t)n * K + k] = f2b(W[i]);
}

__global__ void k_prep_x(const float* __restrict__ x, ushort* __restrict__ xb, int n4) {
    int stride = gridDim.x * blockDim.x;
    for (int i = blockIdx.x * blockDim.x + threadIdx.x; i < n4; i += stride) {
        float4 v = ((const float4*)x)[i];
        uint2 o; o.x = pack2(v.x, v.y); o.y = pack2(v.z, v.w);
        ((uint2*)xb)[i] = o;
    }
}

// ---------------- sort-by-dst pipeline ----------------
__global__ void k_hist(const int* __restrict__ col, int* __restrict__ deg, int E) {
    int stride = gridDim.x * blockDim.x;
    for (int i = blockIdx.x * blockDim.x + threadIdx.x; i < E; i += stride)
        atomicAdd(&deg[col[i]], 1);
}

__global__ void k_bsum(const int* __restrict__ deg, int* __restrict__ bsum, int Nn) {
    __shared__ int red[256];
    int t = threadIdx.x;
    int i = blockIdx.x * 256 + t;
    red[t] = (i < Nn) ? deg[i] : 0;
    __syncthreads();
    for (int s = 128; s > 0; s >>= 1) {
        if (t < s) red[t] += red[t + s];
        __syncthreads();
    }
    if (t == 0) bsum[blockIdx.x] = red[0];
}

// single-block exclusive scan of NB (<=256) block sums
__global__ void k_bscan(const int* __restrict__ bsum, int* __restrict__ bbase, int NB) {
    __shared__ int s[256];
    int t = threadIdx.x;
    int v = (t < NB) ? bsum[t] : 0;
    s[t] = v;
    __syncthreads();
    for (int off = 1; off < 256; off <<= 1) {
        int u = (t >= off) ? s[t - off] : 0;
        __syncthreads();
        s[t] += u;
        __syncthreads();
    }
    if (t < NB) bbase[t] = s[t] - v;
}

__global__ void k_base(const int* __restrict__ deg, const int* __restrict__ bbase,
                       int* __restrict__ base, int Nn) {
    __shared__ int s[256];
    int t = threadIdx.x;
    int i = blockIdx.x * 256 + t;
    int v = (i < Nn) ? deg[i] : 0;
    s[t] = v;
    __syncthreads();
    for (int off = 1; off < 256; off <<= 1) {
        int u = (t >= off) ? s[t - off] : 0;
        __syncthreads();
        s[t] += u;
        __syncthreads();
    }
    if (i < Nn) base[i] = bbase[blockIdx.x] + s[t] - v;
}

__global__ void k_scatter(const int* __restrict__ col, const int* __restrict__ base,
                          int* __restrict__ fill, int* __restrict__ perm, int E) {
    int stride = gridDim.x * blockDim.x;
    for (int e = blockIdx.x * blockDim.x + threadIdx.x; e < E; e += stride) {
        int d = col[e];
        int pos = base[d] + atomicAdd(&fill[d], 1);
        perm[pos] = e;
    }
}

// stats [2][C] (sum, sumsq) -> ss [2][C] (scale, shift); bias cancels in BN.
__global__ void k_fin(const float* __restrict__ stats, const float* __restrict__ g,
                      const float* __restrict__ be, float* __restrict__ ss,
                      int C, float invM) {
    int c = blockIdx.x * blockDim.x + threadIdx.x;
    if (c >= C) return;
    float mean = stats[c] * invM;
    float var  = stats[C + c] * invM - mean * mean;
    float scale = g[c] * rsqrtf(var + EPSV);
    ss[c] = scale;
    ss[C + c] = be[c] - mean * scale;
}

// reduce 128 buckets of [256] (sum|sumsq) then finalize, C=128
__global__ void k_fin1(const float* __restrict__ statsB, const float* __restrict__ g,
                       const float* __restrict__ be, float* __restrict__ ss, float invM) {
    int c = threadIdx.x;   // 128 threads
    float sm = 0.f, sq = 0.f;
    for (int b = 0; b < 128; ++b) {
        sm += statsB[b * 256 + c];
        sq += statsB[b * 256 + 128 + c];
    }
    float mean = sm * invM;
    float var  = sq * invM - mean * mean;
    float scale = g[c] * rsqrtf(var + EPSV);
    ss[c] = scale;
    ss[128 + c] = be[c] - mean * scale;
}

// ---------------- k_xa: xa = x @ W1[:128,:]  ([50k,128] fp32) ----------------
__global__ __launch_bounds__(256) void k_xa(
    const ushort* __restrict__ xb, const ushort* __restrict__ W1t,
    float* __restrict__ xa, int Nn)
{
    __shared__ ushort sA[128][72];
    __shared__ ushort sB[128][72];
    const int tid = threadIdx.x;
    const int lane = tid & 63, wave = tid >> 6;
    const int q = lane >> 4, lm = lane & 15;
    const int wr = wave * 32;
    const int rs = tid >> 1;
    const int kh = (tid & 1) * 32;
    const int m0 = blockIdx.x * 128;
    const int row = m0 + rs;
    const bool valid = row < Nn;

    floatx4 acc[2][8];
#pragma unroll
    for (int a = 0; a < 2; ++a)
#pragma unroll
        for (int b = 0; b < 8; ++b) acc[a][b] = (floatx4){0.f, 0.f, 0.f, 0.f};

#pragma unroll
    for (int kc = 0; kc < 2; ++kc) {
        uint4* dstA = (uint4*)&sA[rs][kh];
        const uint4* srcA = (const uint4*)(xb + (size_t)row * 128 + kc * 64 + kh);
#pragma unroll
        for (int j = 0; j < 4; ++j) {
            uint4 o = {0u, 0u, 0u, 0u};
            if (valid) o = srcA[j];
            dstA[j] = o;
        }
        const uint4* srcB = (const uint4*)(W1t + (size_t)rs * 192 + kc * 64 + kh);
        uint4* dstB = (uint4*)&sB[rs][kh];
#pragma unroll
        for (int j = 0; j < 4; ++j) dstB[j] = srcB[j];
        __syncthreads();
#pragma unroll
        for (int ks = 0; ks < 2; ++ks) {
            short8 a0 = *(const short8*)&sA[wr + lm][ks * 32 + q * 8];
            short8 a1 = *(const short8*)&sA[wr + 16 + lm][ks * 32 + q * 8];
#pragma unroll
            for (int ct = 0; ct < 8; ++ct) {
                short8 b = *(const short8*)&sB[ct * 16 + lm][ks * 32 + q * 8];
                acc[0][ct] = __builtin_amdgcn_mfma_f32_16x16x32_bf16(a0, b, acc[0][ct], 0, 0, 0);
                acc[1][ct] = __builtin_amdgcn_mfma_f32_16x16x32_bf16(a1, b, acc[1][ct], 0, 0, 0);
            }
        }
        __syncthreads();
    }
#pragma unroll
    for (int rt = 0; rt < 2; ++rt)
#pragma unroll
        for (int r = 0; r < 4; ++r) {
            int grow = m0 + wr + rt * 16 + q * 4 + r;
            if (grow < Nn) {
                float* drow = xa + (size_t)grow * 128;
#pragma unroll
                for (int ct = 0; ct < 8; ++ct)
                    drow[ct * 16 + lm] = acc[rt][ct][r];
            }
        }
}

// ---------------- pass 1: t = ea @ W1e (K=64); h = t + xa[src]; col stats ----
// persistent grid-stride blocks; W1e tile persistent in LDS; stats accumulate
// in registers across tiles, one bucketed global atomic per thread at the end.
__global__ __launch_bounds__(256) void k_edge1(
    const float* __restrict__ ea, const int* __restrict__ eidx,
    const ushort* __restrict__ W1t, const float* __restrict__ xa,
    float* __restrict__ statsB, int E, int NT)
{
    __shared__ ushort sA[128][72];
    __shared__ ushort sB[128][72];
    __shared__ int sSrc[128];
    __shared__ float sRed[256];

    const int tid = threadIdx.x;
    const int lane = tid & 63, wave = tid >> 6;
    const int q = lane >> 4, lm = lane & 15;
    const int wr = wave * 32;
    const int rs = tid >> 1;
    const int kh = (tid & 1) * 32;

    {   // persistent B: W1e^T = W1t rows, k = 128..191
        const uint4* srcB = (const uint4*)(W1t + (size_t)rs * 192 + 128 + kh);
        uint4* dstB = (uint4*)&sB[rs][kh];
#pragma unroll
        for (int j = 0; j < 4; ++j) dstB[j] = srcB[j];
    }

    float s1[8], s2[8];
#pragma unroll
    for (int ct = 0; ct < 8; ++ct) { s1[ct] = 0.f; s2[ct] = 0.f; }

    for (int tile = blockIdx.x; tile < NT; tile += gridDim.x) {
        const int e0 = tile * 128;
        __syncthreads();   // protect sA/sSrc from previous tile's readers (also B vis)
        if (tid < 128) {
            int e = e0 + tid;
            sSrc[tid] = (e < E) ? eidx[e] : -1;
        }
        {   // stage A: edge_attr fp32 -> bf16, streaming
            const bool valid = (e0 + rs) < E;
            const float4* srcA = (const float4*)(ea + (size_t)(e0 + rs) * 64 + kh);
            uint4* dstA = (uint4*)&sA[rs][kh];
#pragma unroll
            for (int j = 0; j < 4; ++j) {
                uint4 o = {0u, 0u, 0u, 0u};
                if (valid) {
                    float4 v0 = srcA[2 * j], v1 = srcA[2 * j + 1];
                    o.x = pack2(v0.x, v0.y); o.y = pack2(v0.z, v0.w);
                    o.z = pack2(v1.x, v1.y); o.w = pack2(v1.z, v1.w);
                }
                dstA[j] = o;
            }
        }
        __syncthreads();

        floatx4 acc[2][8];
#pragma unroll
        for (int a = 0; a < 2; ++a)
#pragma unroll
            for (int b = 0; b < 8; ++b) acc[a][b] = (floatx4){0.f, 0.f, 0.f, 0.f};
#pragma unroll
        for (int ks = 0; ks < 2; ++ks) {
            short8 a0 = *(const short8*)&sA[wr + lm][ks * 32 + q * 8];
            short8 a1 = *(const short8*)&sA[wr + 16 + lm][ks * 32 + q * 8];
#pragma unroll
            for (int ct = 0; ct < 8; ++ct) {
                short8 b = *(const short8*)&sB[ct * 16 + lm][ks * 32 + q * 8];
                acc[0][ct] = __builtin_amdgcn_mfma_f32_16x16x32_bf16(a0, b, acc[0][ct], 0, 0, 0);
                acc[1][ct] = __builtin_amdgcn_mfma_f32_16x16x32_bf16(a1, b, acc[1][ct], 0, 0, 0);
            }
        }
        // h = t + xa[src]; accumulate column sum/sumsq in registers
#pragma unroll
        for (int rt = 0; rt < 2; ++rt)
#pragma unroll
            for (int r = 0; r < 4; ++r) {
                int trow = wr + rt * 16 + q * 4 + r;
                int srcn = sSrc[trow];
                if (srcn >= 0) {
                    const float* xr = xa + (size_t)srcn * 128 + lm;
#pragma unroll
                    for (int ct = 0; ct < 8; ++ct) {
                        float v = acc[rt][ct][r] + xr[ct * 16];
                        s1[ct] += v; s2[ct] += v * v;
                    }
                }
            }
    }

    __syncthreads();
    sRed[tid] = 0.f;
    __syncthreads();
#pragma unroll
    for (int ct = 0; ct < 8; ++ct) {
        float sm = s1[ct], sq = s2[ct];
        sm += __shfl_xor(sm, 16, 64); sm += __shfl_xor(sm, 32, 64);
        sq += __shfl_xor(sq, 16, 64); sq += __shfl_xor(sq, 32, 64);
        if (q == 0) {
            atomicAdd(&sRed[ct * 16 + lm], sm);
            atomicAdd(&sRed[128 + ct * 16 + lm], sq);
        }
    }
    __syncthreads();
    atomicAdd(&statsB[(size_t)(blockIdx.x & 127) * 256 + tid], sRed[tid]);
}

// ---------------- pass 2: recompute t over dst-sorted edges, h = t + xa[src],
// apply BN scale/shift + relu, run-length segmented reduce by dst -> sacc ----
__global__ __launch_bounds__(256) void k_edge2(
    const float* __restrict__ ea, const int* __restrict__ eidx,
    const int* __restrict__ perm, const ushort* __restrict__ W1t,
    const float* __restrict__ xa, const float* __restrict__ ss,
    float* __restrict__ sacc, int E, int NT)
{
    __shared__ union SM {
        struct { ushort A[128][72]; ushort B[128][72]; } t;
        float buf[64][132];
    } sm;
    __shared__ int sSrc[128];
    __shared__ int sDst[128];

    const int tid = threadIdx.x;
    const int lane = tid & 63, wave = tid >> 6;
    const int q = lane >> 4, lm = lane & 15;
    const int wr = wave * 32;
    const int rs = tid >> 1;
    const int kh = (tid & 1) * 32;

    float sc[8], sh[8];
#pragma unroll
    for (int ct = 0; ct < 8; ++ct) {
        sc[ct] = ss[ct * 16 + lm];
        sh[ct] = ss[128 + ct * 16 + lm];
    }

    for (int tile = blockIdx.x; tile < NT; tile += gridDim.x) {
        const int e0 = tile * 128;
        __syncthreads();   // protect buf/sSrc/sDst from previous tile's readers
        if (tid < 128) {
            int e = e0 + tid;
            int pe = (e < E) ? perm[e] : -1;
            sSrc[tid] = (pe >= 0) ? eidx[pe] : -1;
            sDst[tid] = (pe >= 0) ? eidx[E + pe] : -1;
        }
        {   // stage A: edge_attr gathered via perm (per-thread load, no LDS dep)
            int e = e0 + rs;
            int pe = (e < E) ? perm[e] : -1;
            const float4* srcA = (const float4*)(ea + (size_t)pe * 64 + kh);
            uint4* dstA = (uint4*)&sm.t.A[rs][kh];
#pragma unroll
            for (int j = 0; j < 4; ++j) {
                uint4 o = {0u, 0u, 0u, 0u};
                if (pe >= 0) {
                    float4 v0 = srcA[2 * j], v1 = srcA[2 * j + 1];
                    o.x = pack2(v0.x, v0.y); o.y = pack2(v0.z, v0.w);
                    o.z = pack2(v1.x, v1.y); o.w = pack2(v1.z, v1.w);
                }
                dstA[j] = o;
            }
            const uint4* srcB = (const uint4*)(W1t + (size_t)rs * 192 + 128 + kh);
            uint4* dstB = (uint4*)&sm.t.B[rs][kh];
#pragma unroll
            for (int j = 0; j < 4; ++j) dstB[j] = srcB[j];
        }
        __syncthreads();

        floatx4 acc[2][8];
#pragma unroll
        for (int a = 0; a < 2; ++a)
#pragma unroll
            for (int b = 0; b < 8; ++b) acc[a][b] = (floatx4){0.f, 0.f, 0.f, 0.f};
#pragma unroll
        for (int ks = 0; ks < 2; ++ks) {
            short8 a0 = *(const short8*)&sm.t.A[wr + lm][ks * 32 + q * 8];
            short8 a1 = *(const short8*)&sm.t.A[wr + 16 + lm][ks * 32 + q * 8];
#pragma unroll
            for (int ct = 0; ct < 8; ++ct) {
                short8 b = *(const short8*)&sm.t.B[ct * 16 + lm][ks * 32 + q * 8];
                acc[0][ct] = __builtin_amdgcn_mfma_f32_16x16x32_bf16(a0, b, acc[0][ct], 0, 0, 0);
                acc[1][ct] = __builtin_amdgcn_mfma_f32_16x16x32_bf16(a1, b, acc[1][ct], 0, 0, 0);
            }
        }
        // h = t + xa[src]
#pragma unroll
        for (int rt = 0; rt < 2; ++rt)
#pragma unroll
            for (int r = 0; r < 4; ++r) {
                int trow = wr + rt * 16 + q * 4 + r;
                int srcn = sSrc[trow];
                if (srcn >= 0) {
                    const float* xr = xa + (size_t)srcn * 128 + lm;
#pragma unroll
                    for (int ct = 0; ct < 8; ++ct)
                        acc[rt][ct][r] += xr[ct * 16];
                }
            }

#pragma unroll
        for (int half = 0; half < 2; ++half) {
            __syncthreads();
            if ((wave >> 1) == half) {          // waves owning rows [half*64, half*64+64)
                int rb = (wave & 1) * 32;
#pragma unroll
                for (int rt = 0; rt < 2; ++rt)
#pragma unroll
                    for (int r = 0; r < 4; ++r) {
                        int rowl = rb + rt * 16 + q * 4 + r;
#pragma unroll
                        for (int ct = 0; ct < 8; ++ct) {
                            float v = fmaxf(fmaf(acc[rt][ct][r], sc[ct], sh[ct]), 0.f);
                            sm.buf[rowl][ct * 16 + lm] = v;
                        }
                    }
            }
            __syncthreads();
            // run-length segmented reduce: dst is sorted within the tile.
            int c = tid & 127, chunk = tid >> 7;
            int rbeg = half * 64 + chunk * 32;
            int cur = sDst[rbeg];
            float run = 0.f;
#pragma unroll 4
            for (int i = 0; i < 32; ++i) {
                int d = sDst[rbeg + i];
                float v = sm.buf[chunk * 32 + i][c];
                if (d != cur) {
                    if (cur >= 0) atomicAdd(&sacc[(size_t)cur * 128 + c], run);
                    run = 0.f; cur = d;
                }
                run += v;
            }
            if (cur >= 0) atomicAdd(&sacc[(size_t)cur * 128 + c], run);
        }
    }
}

// ---------------- GEMM2: [N,256] x [256,256] (+stats2, h2 bf16 out) ----------------
__global__ __launch_bounds__(256) void k_gemm2(
    const ushort* __restrict__ xb, const float* __restrict__ sacc,
    const int* __restrict__ deg, const ushort* __restrict__ W2t,
    float* __restrict__ stats2, ushort* __restrict__ h2, int Nn)
{
    __shared__ ushort sA[128][72];
    __shared__ ushort sB[128][72];
    __shared__ float sRed[256];

    const int tid = threadIdx.x;
    const int m0 = blockIdx.x * 128;
    const int n0 = blockIdx.y * 128;
    const int lane = tid & 63, wave = tid >> 6;
    const int q = lane >> 4, lm = lane & 15;
    const int wr = wave * 32;
    const int rs = tid >> 1;
    const int kh = (tid & 1) * 32;
    const int row = m0 + rs;
    const bool valid = row < Nn;
    float inv = 0.f;
    if (valid) {
        int d = deg[row];
        inv = (d > 0) ? 1.f / (float)d : 0.f;
    }

    floatx4 acc[2][8];
#pragma unroll
    for (int a = 0; a < 2; ++a)
#pragma unroll
        for (int b = 0; b < 8; ++b) acc[a][b] = (floatx4){0.f, 0.f, 0.f, 0.f};

#pragma unroll
    for (int kc = 0; kc < 4; ++kc) {
        uint4* dstA = (uint4*)&sA[rs][kh];
        if (kc < 2) {
            const uint4* src = (const uint4*)(xb + (size_t)row * 128 + kc * 64 + kh);
#pragma unroll
            for (int j = 0; j < 4; ++j) {
                uint4 o = {0u, 0u, 0u, 0u};
                if (valid) o = src[j];
                dstA[j] = o;
            }
        } else {
            const float4* src = (const float4*)(sacc + (size_t)row * 128 + (kc - 2) * 64 + kh);
#pragma unroll
            for (int j = 0; j < 4; ++j) {
                uint4 o = {0u, 0u, 0u, 0u};
                if (valid) {
                    float4 v0 = src[2 * j], v1 = src[2 * j + 1];
                    o.x = pack2(v0.x * inv, v0.y * inv); o.y = pack2(v0.z * inv, v0.w * inv);
                    o.z = pack2(v1.x * inv, v1.y * inv); o.w = pack2(v1.z * inv, v1.w * inv);
                }
                dstA[j] = o;
            }
        }
        {
            const uint4* src = (const uint4*)(W2t + (size_t)(n0 + rs) * 256 + kc * 64 + kh);
            uint4* dstB = (uint4*)&sB[rs][kh];
#pragma unroll
            for (int j = 0; j < 4; ++j) dstB[j] = src[j];
        }
        __syncthreads();
#pragma unroll
        for (int ks = 0; ks < 2; ++ks) {
            short8 a0 = *(const short8*)&sA[wr + lm][ks * 32 + q * 8];
            short8 a1 = *(const short8*)&sA[wr + 16 + lm][ks * 32 + q * 8];
#pragma unroll
            for (int ct = 0; ct < 8; ++ct) {
                short8 b = *(const short8*)&sB[ct * 16 + lm][ks * 32 + q * 8];
                acc[0][ct] = __builtin_amdgcn_mfma_f32_16x16x32_bf16(a0, b, acc[0][ct], 0, 0, 0);
                acc[1][ct] = __builtin_amdgcn_mfma_f32_16x16x32_bf16(a1, b, acc[1][ct], 0, 0, 0);
            }
        }
        __syncthreads();
    }

    sRed[tid] = 0.f;
    __syncthreads();
#pragma unroll
    for (int ct = 0; ct < 8; ++ct) {
        float sm = 0.f, sq = 0.f;
#pragma unroll
        for (int rt = 0; rt < 2; ++rt)
#pragma unroll
            for (int r = 0; r < 4; ++r) {
                float v = acc[rt][ct][r];
                sm += v; sq += v * v;
            }
        sm += __shfl_xor(sm, 16, 64); sm += __shfl_xor(sm, 32, 64);
        sq += __shfl_xor(sq, 16, 64); sq += __shfl_xor(sq, 32, 64);
        if (q == 0) {
            atomicAdd(&sRed[ct * 16 + lm], sm);
            atomicAdd(&sRed[128 + ct * 16 + lm], sq);
        }
    }
#pragma unroll
    for (int rt = 0; rt < 2; ++rt)
#pragma unroll
        for (int r = 0; r < 4; ++r) {
            int grow = m0 + wr + rt * 16 + q * 4 + r;
            if (grow < Nn) {
                ushort* drow = h2 + (size_t)grow * 256 + n0;
#pragma unroll
                for (int ct = 0; ct < 8; ++ct)
                    drow[ct * 16 + lm] = f2b(acc[rt][ct][r]);
            }
        }
    __syncthreads();
    atomicAdd(&stats2[(tid < 128 ? 0 : 256) + n0 + (tid & 127)], sRed[tid]);
}

// ---------------- GEMM3: relu(BN2(h2)) x Wl + bl -> out ----------------
__global__ __launch_bounds__(256) void k_gemm3(
    const ushort* __restrict__ h2, const float* __restrict__ ss2,
    const ushort* __restrict__ Wlt, const float* __restrict__ bl,
    float* __restrict__ out, int Nn)
{
    __shared__ ushort sA[128][72];
    __shared__ ushort sB[128][72];
    const int tid = threadIdx.x;
    const int m0 = blockIdx.x * 128;
    const int lane = tid & 63, wave = tid >> 6;
    const int q = lane >> 4, lm = lane & 15;
    const int wr = wave * 32;
    const int rs = tid >> 1;
    const int kh = (tid & 1) * 32;
    const int row = m0 + rs;
    const bool valid = row < Nn;

    floatx4 acc[2][8];
#pragma unroll
    for (int a = 0; a < 2; ++a)
#pragma unroll
        for (int b = 0; b < 8; ++b) acc[a][b] = (floatx4){0.f, 0.f, 0.f, 0.f};

#pragma unroll
    for (int kc = 0; kc < 4; ++kc) {
        const int kb = kc * 64 + kh;
        uint4* dstA = (uint4*)&sA[rs][kh];
#pragma unroll
        for (int j = 0; j < 4; ++j) {
            uint4 o = {0u, 0u, 0u, 0u};
            if (valid) {
                uint4 vv = ((const uint4*)(h2 + (size_t)row * 256 + kb))[j];
                uint wds[4] = {vv.x, vv.y, vv.z, vv.w};
                uint res[4];
#pragma unroll
                for (int p = 0; p < 4; ++p) {
                    int k0 = kb + j * 8 + p * 2;
                    float f0 = fmaxf(fmaf(b2f((ushort)(wds[p] & 0xFFFFu)), ss2[k0], ss2[256 + k0]), 0.f);
                    float f1 = fmaxf(fmaf(b2f((ushort)(wds[p] >> 16)), ss2[k0 + 1], ss2[256 + k0 + 1]), 0.f);
                    res[p] = pack2(f0, f1);
                }
                o.x = res[0]; o.y = res[1]; o.z = res[2]; o.w = res[3];
            }
            dstA[j] = o;
        }
        {
            const uint4* src = (const uint4*)(Wlt + (size_t)rs * 256 + kc * 64 + kh);
            uint4* dstB = (uint4*)&sB[rs][kh];
#pragma unroll
            for (int j = 0; j < 4; ++j) dstB[j] = src[j];
        }
        __syncthreads();
#pragma unroll
        for (int ks = 0; ks < 2; ++ks) {
            short8 a0 = *(const short8*)&sA[wr + lm][ks * 32 + q * 8];
            short8 a1 = *(const short8*)&sA[wr + 16 + lm][ks * 32 + q * 8];
#pragma unroll
            for (int ct = 0; ct < 8; ++ct) {
                short8 b = *(const short8*)&sB[ct * 16 + lm][ks * 32 + q * 8];
                acc[0][ct] = __builtin_amdgcn_mfma_f32_16x16x32_bf16(a0, b, acc[0][ct], 0, 0, 0);
                acc[1][ct] = __builtin_amdgcn_mfma_f32_16x16x32_bf16(a1, b, acc[1][ct], 0, 0, 0);
            }
        }
        __syncthreads();
    }

    float bias[8];
#pragma unroll
    for (int ct = 0; ct < 8; ++ct) bias[ct] = bl[ct * 16 + lm];
#pragma unroll
    for (int rt = 0; rt < 2; ++rt)
#pragma unroll
        for (int r = 0; r < 4; ++r) {
            int grow = m0 + wr + rt * 16 + q * 4 + r;
            if (grow < Nn) {
                float* drow = out + (size_t)grow * 128;
#pragma unroll
                for (int ct = 0; ct < 8; ++ct)
                    drow[ct * 16 + lm] = fmaxf(acc[rt][ct][r] + bias[ct], 0.f);
            }
        }
}

extern "C" void kernel_launch(void* const* d_in, const int* in_sizes, int n_in,
                              void* d_out, int out_size, void* d_ws, size_t ws_size,
                              hipStream_t stream) {
    const float* x   = (const float*)d_in[0];
    const int* eidx  = (const int*)d_in[1];
    const float* ea  = (const float*)d_in[2];
    const float* W1  = (const float*)d_in[5];
    const float* g1  = (const float*)d_in[7];
    const float* be1 = (const float*)d_in[8];
    const float* W2  = (const float*)d_in[9];
    const float* g2  = (const float*)d_in[11];
    const float* be2 = (const float*)d_in[12];
    const float* Wl  = (const float*)d_in[13];
    const float* bl  = (const float*)d_in[14];

    const int Nn = in_sizes[0] / 128;   // 50000
    const int E  = in_sizes[1] / 2;     // 1600000
    const int NB = (Nn + 255) / 256;    // 196
    const int NT = (E + 127) / 128;     // 12500 (exact: E % 128 == 0)

    char* w = (char*)d_ws;
    // ---- zero region ----
    float* s_acc   = (float*)w;  w += (size_t)Nn * 128 * 4;
    int*   deg     = (int*)w;    w += (size_t)Nn * 4;
    int*   fill    = (int*)w;    w += (size_t)Nn * 4;
    float* stats1B = (float*)w;  w += (size_t)128 * 256 * 4;
    float* stats2  = (float*)w;  w += 512 * 4;
    size_t zbytes = (size_t)(w - (char*)d_ws);
    // ---- fully-overwritten region ----
    float* ss1    = (float*)w;  w += 256 * 4;
    float* ss2    = (float*)w;  w += 512 * 4;
    ushort* W1t   = (ushort*)w; w += 128 * 192 * 2;
    ushort* W2t   = (ushort*)w; w += 256 * 256 * 2;
    ushort* Wlt   = (ushort*)w; w += 128 * 256 * 2;
    ushort* xb    = (ushort*)w; w += (size_t)Nn * 128 * 2;
    ushort* h2    = (ushort*)w; w += (size_t)Nn * 256 * 2;
    int*   base   = (int*)w;    w += (size_t)Nn * 4;
    int*   bsum   = (int*)w;    w += (size_t)NB * 4;
    int*   bbase  = (int*)w;    w += (size_t)NB * 4;
    int*   perm   = (int*)w;    w += (size_t)E * 4;
    float* xa     = (float*)w;  w += (size_t)Nn * 128 * 4;
    (void)ws_size; (void)n_in; (void)out_size;

    hipMemsetAsync(d_ws, 0, zbytes, stream);

    const int GS = 2048;   // grid-stride WG count for flat kernels

    k_prep_w<<<(192 * 128 + 255) / 256, 256, 0, stream>>>(W1, W1t, 192, 128);
    k_prep_w<<<(256 * 256 + 255) / 256, 256, 0, stream>>>(W2, W2t, 256, 256);
    k_prep_w<<<(256 * 128 + 255) / 256, 256, 0, stream>>>(Wl, Wlt, 256, 128);
    k_prep_x<<<GS, 256, 0, stream>>>(x, xb, Nn * 128 / 4);

    // sort edges by dst: histogram -> scan -> scatter
    k_hist<<<GS, 256, 0, stream>>>(eidx + E, deg, E);
    k_bsum<<<NB, 256, 0, stream>>>(deg, bsum, Nn);
    k_bscan<<<1, 256, 0, stream>>>(bsum, bbase, NB);
    k_base<<<NB, 256, 0, stream>>>(deg, bbase, base, Nn);
    k_scatter<<<GS, 256, 0, stream>>>(eidx + E, base, fill, perm, E);

    // xa = x @ W1[:128,:]  (hoisted node-part of GEMM1)
    k_xa<<<(Nn + 127) / 128, 256, 0, stream>>>(xb, W1t, xa, Nn);

    // pass 1: per-edge K=64 GEMM + column stats (persistent grid-stride)
    k_edge1<<<GS, 256, 0, stream>>>(ea, eidx, W1t, xa, stats1B, E, NT);
    k_fin1<<<1, 128, 0, stream>>>(stats1B, g1, be1, ss1, 1.0f / (float)E);
    // pass 2: recompute over dst-sorted edges, BN+relu, segmented scatter
    k_edge2<<<GS, 256, 0, stream>>>(ea, eidx, perm, W1t, xa, ss1, s_acc, E, NT);

    dim3 grid2((Nn + 127) / 128, 2);
    k_gemm2<<<grid2, 256, 0, stream>>>(xb, s_acc, deg, W2t, stats2, h2, Nn);
    k_fin<<<1, 256, 0, stream>>>(stats2, g2, be2, ss2, 256, 1.0f / (float)Nn);
    k_gemm3<<<(Nn + 127) / 128, 256, 0, stream>>>(h2, ss2, Wlt, bl, (float*)d_out, Nn);
}

// Round 2
// 1327.556 us; speedup vs baseline: 1.1809x; 1.1809x over previous
//
#include <hip/hip_runtime.h>
#include <stdint.h>

#define EPSV 1e-5f

typedef short short8 __attribute__((ext_vector_type(8)));
typedef float floatx4 __attribute__((ext_vector_type(4)));

static __device__ __forceinline__ ushort f2b(float f) {
    union { float f; uint32_t u; } v; v.f = f;
    return (ushort)((v.u + 0x7FFFu + ((v.u >> 16) & 1u)) >> 16);
}
static __device__ __forceinline__ uint pack2(float a, float b) {
    return (uint)f2b(a) | ((uint)f2b(b) << 16);
}
static __device__ __forceinline__ float b2f(ushort b) {
    union { uint32_t u; float f; } v; v.u = ((uint32_t)b) << 16;
    return v.f;
}

// ---------------- prep kernels ----------------
__global__ void k_prep_w(const float* __restrict__ W, ushort* __restrict__ Wt,
                         int K, int Nc) {
    int i = blockIdx.x * blockDim.x + threadIdx.x;
    if (i >= K * Nc) return;
    int n = i % Nc, k = i / Nc;
    Wt[(size_t)n * K + k] = f2b(W[i]);
}

__global__ void k_prep_x(const float* __restrict__ x, ushort* __restrict__ xb, int n4) {
    int stride = gridDim.x * blockDim.x;
    for (int i = blockIdx.x * blockDim.x + threadIdx.x; i < n4; i += stride) {
        float4 v = ((const float4*)x)[i];
        uint2 o; o.x = pack2(v.x, v.y); o.y = pack2(v.z, v.w);
        ((uint2*)xb)[i] = o;
    }
}

// ---------------- sort-by-dst pipeline ----------------
__global__ void k_hist(const int* __restrict__ col, int* __restrict__ deg, int E) {
    int stride = gridDim.x * blockDim.x;
    for (int i = blockIdx.x * blockDim.x + threadIdx.x; i < E; i += stride)
        atomicAdd(&deg[col[i]], 1);
}

__global__ void k_bsum(const int* __restrict__ deg, int* __restrict__ bsum, int Nn) {
    __shared__ int red[256];
    int t = threadIdx.x;
    int i = blockIdx.x * 256 + t;
    red[t] = (i < Nn) ? deg[i] : 0;
    __syncthreads();
    for (int s = 128; s > 0; s >>= 1) {
        if (t < s) red[t] += red[t + s];
        __syncthreads();
    }
    if (t == 0) bsum[blockIdx.x] = red[0];
}

__global__ void k_bscan(const int* __restrict__ bsum, int* __restrict__ bbase, int NB) {
    __shared__ int s[256];
    int t = threadIdx.x;
    int v = (t < NB) ? bsum[t] : 0;
    s[t] = v;
    __syncthreads();
    for (int off = 1; off < 256; off <<= 1) {
        int u = (t >= off) ? s[t - off] : 0;
        __syncthreads();
        s[t] += u;
        __syncthreads();
    }
    if (t < NB) bbase[t] = s[t] - v;
}

__global__ void k_base(const int* __restrict__ deg, const int* __restrict__ bbase,
                       int* __restrict__ base, int Nn) {
    __shared__ int s[256];
    int t = threadIdx.x;
    int i = blockIdx.x * 256 + t;
    int v = (i < Nn) ? deg[i] : 0;
    s[t] = v;
    __syncthreads();
    for (int off = 1; off < 256; off <<= 1) {
        int u = (t >= off) ? s[t - off] : 0;
        __syncthreads();
        s[t] += u;
        __syncthreads();
    }
    if (i < Nn) base[i] = bbase[blockIdx.x] + s[t] - v;
}

// extended: also writes src/dst in sorted position (when srcs != nullptr)
__global__ void k_scatter(const int* __restrict__ eidx, const int* __restrict__ base,
                          int* __restrict__ fill, int* __restrict__ perm,
                          int* __restrict__ srcs, int* __restrict__ dsts, int E) {
    int stride = gridDim.x * blockDim.x;
    for (int e = blockIdx.x * blockDim.x + threadIdx.x; e < E; e += stride) {
        int d = eidx[E + e];
        int pos = base[d] + atomicAdd(&fill[d], 1);
        perm[pos] = e;
        if (srcs) { srcs[pos] = eidx[e]; dsts[pos] = d; }
    }
}

// stats [2][C] (sum, sumsq) -> ss [2][C] (scale, shift)
__global__ void k_fin(const float* __restrict__ stats, const float* __restrict__ g,
                      const float* __restrict__ be, float* __restrict__ ss,
                      int C, float invM) {
    int c = blockIdx.x * blockDim.x + threadIdx.x;
    if (c >= C) return;
    float mean = stats[c] * invM;
    float var  = stats[C + c] * invM - mean * mean;
    float scale = g[c] * rsqrtf(var + EPSV);
    ss[c] = scale;
    ss[C + c] = be[c] - mean * scale;
}

__global__ void k_fin1(const float* __restrict__ statsB, const float* __restrict__ g,
                       const float* __restrict__ be, float* __restrict__ ss, float invM) {
    int c = threadIdx.x;   // 128 threads
    float sm = 0.f, sq = 0.f;
    for (int b = 0; b < 128; ++b) {
        sm += statsB[b * 256 + c];
        sq += statsB[b * 256 + 128 + c];
    }
    float mean = sm * invM;
    float var  = sq * invM - mean * mean;
    float scale = g[c] * rsqrtf(var + EPSV);
    ss[c] = scale;
    ss[128 + c] = be[c] - mean * scale;
}

// ---------------- k_xa: xa = x @ W1[:128,:]  (fp32 or bf16 out) ----------------
template <bool BF>
__global__ __launch_bounds__(256) void k_xa(
    const ushort* __restrict__ xb, const ushort* __restrict__ W1t,
    void* __restrict__ out, int Nn)
{
    __shared__ ushort sA[128][72];
    __shared__ ushort sB[128][72];
    const int tid = threadIdx.x;
    const int lane = tid & 63, wave = tid >> 6;
    const int q = lane >> 4, lm = lane & 15;
    const int wr = wave * 32;
    const int rs = tid >> 1;
    const int kh = (tid & 1) * 32;
    const int m0 = blockIdx.x * 128;
    const int row = m0 + rs;
    const bool valid = row < Nn;

    floatx4 acc[2][8];
#pragma unroll
    for (int a = 0; a < 2; ++a)
#pragma unroll
        for (int b = 0; b < 8; ++b) acc[a][b] = (floatx4){0.f, 0.f, 0.f, 0.f};

#pragma unroll
    for (int kc = 0; kc < 2; ++kc) {
        uint4* dstA = (uint4*)&sA[rs][kh];
        const uint4* srcA = (const uint4*)(xb + (size_t)row * 128 + kc * 64 + kh);
#pragma unroll
        for (int j = 0; j < 4; ++j) {
            uint4 o = {0u, 0u, 0u, 0u};
            if (valid) o = srcA[j];
            dstA[j] = o;
        }
        const uint4* srcB = (const uint4*)(W1t + (size_t)rs * 192 + kc * 64 + kh);
        uint4* dstB = (uint4*)&sB[rs][kh];
#pragma unroll
        for (int j = 0; j < 4; ++j) dstB[j] = srcB[j];
        __syncthreads();
#pragma unroll
        for (int ks = 0; ks < 2; ++ks) {
            short8 a0 = *(const short8*)&sA[wr + lm][ks * 32 + q * 8];
            short8 a1 = *(const short8*)&sA[wr + 16 + lm][ks * 32 + q * 8];
#pragma unroll
            for (int ct = 0; ct < 8; ++ct) {
                short8 b = *(const short8*)&sB[ct * 16 + lm][ks * 32 + q * 8];
                acc[0][ct] = __builtin_amdgcn_mfma_f32_16x16x32_bf16(a0, b, acc[0][ct], 0, 0, 0);
                acc[1][ct] = __builtin_amdgcn_mfma_f32_16x16x32_bf16(a1, b, acc[1][ct], 0, 0, 0);
            }
        }
        __syncthreads();
    }
#pragma unroll
    for (int rt = 0; rt < 2; ++rt)
#pragma unroll
        for (int r = 0; r < 4; ++r) {
            int grow = m0 + wr + rt * 16 + q * 4 + r;
            if (grow < Nn) {
                if (BF) {
                    ushort* drow = (ushort*)out + (size_t)grow * 128;
#pragma unroll
                    for (int ct = 0; ct < 8; ++ct)
                        drow[ct * 16 + lm] = f2b(acc[rt][ct][r]);
                } else {
                    float* drow = (float*)out + (size_t)grow * 128;
#pragma unroll
                    for (int ct = 0; ct < 8; ++ct)
                        drow[ct * 16 + lm] = acc[rt][ct][r];
                }
            }
        }
}

// ============ MAIN PATH ============
// k_edgeA: dst-sorted single compute pass. t = ea@W1e (K=64, MFMA),
// h = t + xab[src] (LDS-staged bf16 gather), register BN stats, h -> global bf16.
__global__ __launch_bounds__(256) void k_edgeA(
    const float* __restrict__ ea, const int* __restrict__ perm,
    const int* __restrict__ srcs, const ushort* __restrict__ W1t,
    const ushort* __restrict__ xab, float* __restrict__ statsB,
    ushort* __restrict__ hs, int E, int NT)
{
    __shared__ union SM {
        struct { ushort A[128][72]; ushort B[128][72]; } t;
        ushort X[128][132];   // 264B row stride: q-groups land on disjoint banks
    } sm;
    __shared__ int sPE[128];
    __shared__ int sSrc[128];
    __shared__ float sRed[256];

    const int tid = threadIdx.x;
    const int lane = tid & 63, wave = tid >> 6;
    const int q = lane >> 4, lm = lane & 15;
    const int wr = wave * 32;
    const int rs = tid >> 1;
    const int half = tid & 1;
    const int kh = half * 32;

    float s1[8], s2[8];
#pragma unroll
    for (int ct = 0; ct < 8; ++ct) { s1[ct] = 0.f; s2[ct] = 0.f; }

    for (int tile = blockIdx.x; tile < NT; tile += gridDim.x) {
        const int e0 = tile * 128;
        __syncthreads();   // protect LDS from previous tile's readers
        if (tid < 128) {
            int e = e0 + tid;
            sPE[tid]  = (e < E) ? perm[e] : -1;
            sSrc[tid] = (e < E) ? srcs[e] : -1;
        }
        __syncthreads();
        {   // stage A: ea gathered via perm (fp32 -> bf16)
            int pe = sPE[rs];
            const float4* srcA = (const float4*)(ea + (size_t)pe * 64 + kh);
            uint4* dstA = (uint4*)&sm.t.A[rs][kh];
#pragma unroll
            for (int j = 0; j < 4; ++j) {
                uint4 o = {0u, 0u, 0u, 0u};
                if (pe >= 0) {
                    float4 v0 = srcA[2 * j], v1 = srcA[2 * j + 1];
                    o.x = pack2(v0.x, v0.y); o.y = pack2(v0.z, v0.w);
                    o.z = pack2(v1.x, v1.y); o.w = pack2(v1.z, v1.w);
                }
                dstA[j] = o;
            }
            const uint4* srcB = (const uint4*)(W1t + (size_t)rs * 192 + 128 + kh);
            uint4* dstB = (uint4*)&sm.t.B[rs][kh];
#pragma unroll
            for (int j = 0; j < 4; ++j) dstB[j] = srcB[j];
        }
        __syncthreads();

        floatx4 acc[2][8];
#pragma unroll
        for (int a = 0; a < 2; ++a)
#pragma unroll
            for (int b = 0; b < 8; ++b) acc[a][b] = (floatx4){0.f, 0.f, 0.f, 0.f};
#pragma unroll
        for (int ks = 0; ks < 2; ++ks) {
            short8 a0 = *(const short8*)&sm.t.A[wr + lm][ks * 32 + q * 8];
            short8 a1 = *(const short8*)&sm.t.A[wr + 16 + lm][ks * 32 + q * 8];
#pragma unroll
            for (int ct = 0; ct < 8; ++ct) {
                short8 b = *(const short8*)&sm.t.B[ct * 16 + lm][ks * 32 + q * 8];
                acc[0][ct] = __builtin_amdgcn_mfma_f32_16x16x32_bf16(a0, b, acc[0][ct], 0, 0, 0);
                acc[1][ct] = __builtin_amdgcn_mfma_f32_16x16x32_bf16(a1, b, acc[1][ct], 0, 0, 0);
            }
        }
        __syncthreads();   // MFMA reads of A/B done; X overwrites the union
        {   // stage X: xab rows gathered via src, coalesced uint4 global loads
            int s = sSrc[rs];
            const uint4* gsrc = (const uint4*)(xab + (size_t)(s < 0 ? 0 : s) * 128 + half * 64);
            uint2* ldst = (uint2*)((char*)&sm.X[rs][0] + half * 128);
#pragma unroll
            for (int j = 0; j < 8; ++j) {
                uint4 v = {0u, 0u, 0u, 0u};
                if (s >= 0) v = gsrc[j];
                ldst[2 * j]     = (uint2){v.x, v.y};
                ldst[2 * j + 1] = (uint2){v.z, v.w};
            }
        }
        __syncthreads();
        // add xab, accumulate stats, store h (bf16, sorted order)
#pragma unroll
        for (int rt = 0; rt < 2; ++rt)
#pragma unroll
            for (int r = 0; r < 4; ++r) {
                int trow = wr + rt * 16 + q * 4 + r;
                if (sPE[trow] >= 0) {
                    ushort* drow = hs + (size_t)(e0 + trow) * 128;
#pragma unroll
                    for (int ct = 0; ct < 8; ++ct) {
                        float v = acc[rt][ct][r] + b2f(sm.X[trow][ct * 16 + lm]);
                        s1[ct] += v; s2[ct] += v * v;
                        drow[ct * 16 + lm] = f2b(v);
                    }
                }
            }
    }

    __syncthreads();
    sRed[tid] = 0.f;
    __syncthreads();
#pragma unroll
    for (int ct = 0; ct < 8; ++ct) {
        float sm2 = s1[ct], sq2 = s2[ct];
        sm2 += __shfl_xor(sm2, 16, 64); sm2 += __shfl_xor(sm2, 32, 64);
        sq2 += __shfl_xor(sq2, 16, 64); sq2 += __shfl_xor(sq2, 32, 64);
        if (q == 0) {
            atomicAdd(&sRed[ct * 16 + lm], sm2);
            atomicAdd(&sRed[128 + ct * 16 + lm], sq2);
        }
    }
    __syncthreads();
    atomicAdd(&statsB[(size_t)(blockIdx.x & 127) * 256 + tid], sRed[tid]);
}

// k_edgeB: stream sorted h, BN+relu, run-length segmented reduce by dst -> sacc
__global__ __launch_bounds__(256) void k_edgeB(
    const ushort* __restrict__ hs, const int* __restrict__ dsts,
    const float* __restrict__ ss, float* __restrict__ sacc, int E, int NT)
{
    __shared__ int sDst[128];
    const int tid = threadIdx.x;
    const int c = tid & 127;
    const int chunk = tid >> 7;
    const float sc = ss[c], sh = ss[128 + c];

    for (int tile = blockIdx.x; tile < NT; tile += gridDim.x) {
        const int e0 = tile * 128;
        __syncthreads();
        if (tid < 128) {
            int e = e0 + tid;
            sDst[tid] = (e < E) ? dsts[e] : -1;
        }
        __syncthreads();
        const int rbeg = chunk * 64;
        int cur = sDst[rbeg];
        float run = 0.f;
#pragma unroll 4
        for (int i = 0; i < 64; ++i) {
            int d = sDst[rbeg + i];
            float v = 0.f;
            if (d >= 0) {
                float hv = b2f(hs[(size_t)(e0 + rbeg + i) * 128 + c]);
                v = fmaxf(fmaf(hv, sc, sh), 0.f);
            }
            if (d != cur) {
                if (cur >= 0) atomicAdd(&sacc[(size_t)cur * 128 + c], run);
                run = 0.f; cur = d;
            }
            run += v;
        }
        if (cur >= 0) atomicAdd(&sacc[(size_t)cur * 128 + c], run);
    }
}

// ============ FALLBACK PATH (round-1 kernels, used only if ws too small) ============
__global__ __launch_bounds__(256) void k_edge1(
    const float* __restrict__ ea, const int* __restrict__ eidx,
    const ushort* __restrict__ W1t, const float* __restrict__ xa,
    float* __restrict__ statsB, int E, int NT)
{
    __shared__ ushort sA[128][72];
    __shared__ ushort sB[128][72];
    __shared__ int sSrc[128];
    __shared__ float sRed[256];

    const int tid = threadIdx.x;
    const int lane = tid & 63, wave = tid >> 6;
    const int q = lane >> 4, lm = lane & 15;
    const int wr = wave * 32;
    const int rs = tid >> 1;
    const int kh = (tid & 1) * 32;

    {
        const uint4* srcB = (const uint4*)(W1t + (size_t)rs * 192 + 128 + kh);
        uint4* dstB = (uint4*)&sB[rs][kh];
#pragma unroll
        for (int j = 0; j < 4; ++j) dstB[j] = srcB[j];
    }

    float s1[8], s2[8];
#pragma unroll
    for (int ct = 0; ct < 8; ++ct) { s1[ct] = 0.f; s2[ct] = 0.f; }

    for (int tile = blockIdx.x; tile < NT; tile += gridDim.x) {
        const int e0 = tile * 128;
        __syncthreads();
        if (tid < 128) {
            int e = e0 + tid;
            sSrc[tid] = (e < E) ? eidx[e] : -1;
        }
        {
            const bool valid = (e0 + rs) < E;
            const float4* srcA = (const float4*)(ea + (size_t)(e0 + rs) * 64 + kh);
            uint4* dstA = (uint4*)&sA[rs][kh];
#pragma unroll
            for (int j = 0; j < 4; ++j) {
                uint4 o = {0u, 0u, 0u, 0u};
                if (valid) {
                    float4 v0 = srcA[2 * j], v1 = srcA[2 * j + 1];
                    o.x = pack2(v0.x, v0.y); o.y = pack2(v0.z, v0.w);
                    o.z = pack2(v1.x, v1.y); o.w = pack2(v1.z, v1.w);
                }
                dstA[j] = o;
            }
        }
        __syncthreads();

        floatx4 acc[2][8];
#pragma unroll
        for (int a = 0; a < 2; ++a)
#pragma unroll
            for (int b = 0; b < 8; ++b) acc[a][b] = (floatx4){0.f, 0.f, 0.f, 0.f};
#pragma unroll
        for (int ks = 0; ks < 2; ++ks) {
            short8 a0 = *(const short8*)&sA[wr + lm][ks * 32 + q * 8];
            short8 a1 = *(const short8*)&sA[wr + 16 + lm][ks * 32 + q * 8];
#pragma unroll
            for (int ct = 0; ct < 8; ++ct) {
                short8 b = *(const short8*)&sB[ct * 16 + lm][ks * 32 + q * 8];
                acc[0][ct] = __builtin_amdgcn_mfma_f32_16x16x32_bf16(a0, b, acc[0][ct], 0, 0, 0);
                acc[1][ct] = __builtin_amdgcn_mfma_f32_16x16x32_bf16(a1, b, acc[1][ct], 0, 0, 0);
            }
        }
#pragma unroll
        for (int rt = 0; rt < 2; ++rt)
#pragma unroll
            for (int r = 0; r < 4; ++r) {
                int trow = wr + rt * 16 + q * 4 + r;
                int srcn = sSrc[trow];
                if (srcn >= 0) {
                    const float* xr = xa + (size_t)srcn * 128 + lm;
#pragma unroll
                    for (int ct = 0; ct < 8; ++ct) {
                        float v = acc[rt][ct][r] + xr[ct * 16];
                        s1[ct] += v; s2[ct] += v * v;
                    }
                }
            }
    }

    __syncthreads();
    sRed[tid] = 0.f;
    __syncthreads();
#pragma unroll
    for (int ct = 0; ct < 8; ++ct) {
        float sm = s1[ct], sq = s2[ct];
        sm += __shfl_xor(sm, 16, 64); sm += __shfl_xor(sm, 32, 64);
        sq += __shfl_xor(sq, 16, 64); sq += __shfl_xor(sq, 32, 64);
        if (q == 0) {
            atomicAdd(&sRed[ct * 16 + lm], sm);
            atomicAdd(&sRed[128 + ct * 16 + lm], sq);
        }
    }
    __syncthreads();
    atomicAdd(&statsB[(size_t)(blockIdx.x & 127) * 256 + tid], sRed[tid]);
}

__global__ __launch_bounds__(256) void k_edge2(
    const float* __restrict__ ea, const int* __restrict__ eidx,
    const int* __restrict__ perm, const ushort* __restrict__ W1t,
    const float* __restrict__ xa, const float* __restrict__ ss,
    float* __restrict__ sacc, int E, int NT)
{
    __shared__ union SM {
        struct { ushort A[128][72]; ushort B[128][72]; } t;
        float buf[64][132];
    } sm;
    __shared__ int sSrc[128];
    __shared__ int sDst[128];

    const int tid = threadIdx.x;
    const int lane = tid & 63, wave = tid >> 6;
    const int q = lane >> 4, lm = lane & 15;
    const int wr = wave * 32;
    const int rs = tid >> 1;
    const int kh = (tid & 1) * 32;

    float sc[8], sh[8];
#pragma unroll
    for (int ct = 0; ct < 8; ++ct) {
        sc[ct] = ss[ct * 16 + lm];
        sh[ct] = ss[128 + ct * 16 + lm];
    }

    for (int tile = blockIdx.x; tile < NT; tile += gridDim.x) {
        const int e0 = tile * 128;
        __syncthreads();
        if (tid < 128) {
            int e = e0 + tid;
            int pe = (e < E) ? perm[e] : -1;
            sSrc[tid] = (pe >= 0) ? eidx[pe] : -1;
            sDst[tid] = (pe >= 0) ? eidx[E + pe] : -1;
        }
        {
            int e = e0 + rs;
            int pe = (e < E) ? perm[e] : -1;
            const float4* srcA = (const float4*)(ea + (size_t)pe * 64 + kh);
            uint4* dstA = (uint4*)&sm.t.A[rs][kh];
#pragma unroll
            for (int j = 0; j < 4; ++j) {
                uint4 o = {0u, 0u, 0u, 0u};
                if (pe >= 0) {
                    float4 v0 = srcA[2 * j], v1 = srcA[2 * j + 1];
                    o.x = pack2(v0.x, v0.y); o.y = pack2(v0.z, v0.w);
                    o.z = pack2(v1.x, v1.y); o.w = pack2(v1.z, v1.w);
                }
                dstA[j] = o;
            }
            const uint4* srcB = (const uint4*)(W1t + (size_t)rs * 192 + 128 + kh);
            uint4* dstB = (uint4*)&sm.t.B[rs][kh];
#pragma unroll
            for (int j = 0; j < 4; ++j) dstB[j] = srcB[j];
        }
        __syncthreads();

        floatx4 acc[2][8];
#pragma unroll
        for (int a = 0; a < 2; ++a)
#pragma unroll
            for (int b = 0; b < 8; ++b) acc[a][b] = (floatx4){0.f, 0.f, 0.f, 0.f};
#pragma unroll
        for (int ks = 0; ks < 2; ++ks) {
            short8 a0 = *(const short8*)&sm.t.A[wr + lm][ks * 32 + q * 8];
            short8 a1 = *(const short8*)&sm.t.A[wr + 16 + lm][ks * 32 + q * 8];
#pragma unroll
            for (int ct = 0; ct < 8; ++ct) {
                short8 b = *(const short8*)&sm.t.B[ct * 16 + lm][ks * 32 + q * 8];
                acc[0][ct] = __builtin_amdgcn_mfma_f32_16x16x32_bf16(a0, b, acc[0][ct], 0, 0, 0);
                acc[1][ct] = __builtin_amdgcn_mfma_f32_16x16x32_bf16(a1, b, acc[1][ct], 0, 0, 0);
            }
        }
#pragma unroll
        for (int rt = 0; rt < 2; ++rt)
#pragma unroll
            for (int r = 0; r < 4; ++r) {
                int trow = wr + rt * 16 + q * 4 + r;
                int srcn = sSrc[trow];
                if (srcn >= 0) {
                    const float* xr = xa + (size_t)srcn * 128 + lm;
#pragma unroll
                    for (int ct = 0; ct < 8; ++ct)
                        acc[rt][ct][r] += xr[ct * 16];
                }
            }

#pragma unroll
        for (int half = 0; half < 2; ++half) {
            __syncthreads();
            if ((wave >> 1) == half) {
                int rb = (wave & 1) * 32;
#pragma unroll
                for (int rt = 0; rt < 2; ++rt)
#pragma unroll
                    for (int r = 0; r < 4; ++r) {
                        int rowl = rb + rt * 16 + q * 4 + r;
#pragma unroll
                        for (int ct = 0; ct < 8; ++ct) {
                            float v = fmaxf(fmaf(acc[rt][ct][r], sc[ct], sh[ct]), 0.f);
                            sm.buf[rowl][ct * 16 + lm] = v;
                        }
                    }
            }
            __syncthreads();
            int c = tid & 127, chunk = tid >> 7;
            int rbeg = half * 64 + chunk * 32;
            int cur = sDst[rbeg];
            float run = 0.f;
#pragma unroll 4
            for (int i = 0; i < 32; ++i) {
                int d = sDst[rbeg + i];
                float v = sm.buf[chunk * 32 + i][c];
                if (d != cur) {
                    if (cur >= 0) atomicAdd(&sacc[(size_t)cur * 128 + c], run);
                    run = 0.f; cur = d;
                }
                run += v;
            }
            if (cur >= 0) atomicAdd(&sacc[(size_t)cur * 128 + c], run);
        }
    }
}

// ---------------- GEMM2: [N,256] x [256,256] (+stats2, h2 bf16 out) ----------------
__global__ __launch_bounds__(256) void k_gemm2(
    const ushort* __restrict__ xb, const float* __restrict__ sacc,
    const int* __restrict__ deg, const ushort* __restrict__ W2t,
    float* __restrict__ stats2, ushort* __restrict__ h2, int Nn)
{
    __shared__ ushort sA[128][72];
    __shared__ ushort sB[128][72];
    __shared__ float sRed[256];

    const int tid = threadIdx.x;
    const int m0 = blockIdx.x * 128;
    const int n0 = blockIdx.y * 128;
    const int lane = tid & 63, wave = tid >> 6;
    const int q = lane >> 4, lm = lane & 15;
    const int wr = wave * 32;
    const int rs = tid >> 1;
    const int kh = (tid & 1) * 32;
    const int row = m0 + rs;
    const bool valid = row < Nn;
    float inv = 0.f;
    if (valid) {
        int d = deg[row];
        inv = (d > 0) ? 1.f / (float)d : 0.f;
    }

    floatx4 acc[2][8];
#pragma unroll
    for (int a = 0; a < 2; ++a)
#pragma unroll
        for (int b = 0; b < 8; ++b) acc[a][b] = (floatx4){0.f, 0.f, 0.f, 0.f};

#pragma unroll
    for (int kc = 0; kc < 4; ++kc) {
        uint4* dstA = (uint4*)&sA[rs][kh];
        if (kc < 2) {
            const uint4* src = (const uint4*)(xb + (size_t)row * 128 + kc * 64 + kh);
#pragma unroll
            for (int j = 0; j < 4; ++j) {
                uint4 o = {0u, 0u, 0u, 0u};
                if (valid) o = src[j];
                dstA[j] = o;
            }
        } else {
            const float4* src = (const float4*)(sacc + (size_t)row * 128 + (kc - 2) * 64 + kh);
#pragma unroll
            for (int j = 0; j < 4; ++j) {
                uint4 o = {0u, 0u, 0u, 0u};
                if (valid) {
                    float4 v0 = src[2 * j], v1 = src[2 * j + 1];
                    o.x = pack2(v0.x * inv, v0.y * inv); o.y = pack2(v0.z * inv, v0.w * inv);
                    o.z = pack2(v1.x * inv, v1.y * inv); o.w = pack2(v1.z * inv, v1.w * inv);
                }
                dstA[j] = o;
            }
        }
        {
            const uint4* src = (const uint4*)(W2t + (size_t)(n0 + rs) * 256 + kc * 64 + kh);
            uint4* dstB = (uint4*)&sB[rs][kh];
#pragma unroll
            for (int j = 0; j < 4; ++j) dstB[j] = src[j];
        }
        __syncthreads();
#pragma unroll
        for (int ks = 0; ks < 2; ++ks) {
            short8 a0 = *(const short8*)&sA[wr + lm][ks * 32 + q * 8];
            short8 a1 = *(const short8*)&sA[wr + 16 + lm][ks * 32 + q * 8];
#pragma unroll
            for (int ct = 0; ct < 8; ++ct) {
                short8 b = *(const short8*)&sB[ct * 16 + lm][ks * 32 + q * 8];
                acc[0][ct] = __builtin_amdgcn_mfma_f32_16x16x32_bf16(a0, b, acc[0][ct], 0, 0, 0);
                acc[1][ct] = __builtin_amdgcn_mfma_f32_16x16x32_bf16(a1, b, acc[1][ct], 0, 0, 0);
            }
        }
        __syncthreads();
    }

    sRed[tid] = 0.f;
    __syncthreads();
#pragma unroll
    for (int ct = 0; ct < 8; ++ct) {
        float sm = 0.f, sq = 0.f;
#pragma unroll
        for (int rt = 0; rt < 2; ++rt)
#pragma unroll
            for (int r = 0; r < 4; ++r) {
                float v = acc[rt][ct][r];
                sm += v; sq += v * v;
            }
        sm += __shfl_xor(sm, 16, 64); sm += __shfl_xor(sm, 32, 64);
        sq += __shfl_xor(sq, 16, 64); sq += __shfl_xor(sq, 32, 64);
        if (q == 0) {
            atomicAdd(&sRed[ct * 16 + lm], sm);
            atomicAdd(&sRed[128 + ct * 16 + lm], sq);
        }
    }
#pragma unroll
    for (int rt = 0; rt < 2; ++rt)
#pragma unroll
        for (int r = 0; r < 4; ++r) {
            int grow = m0 + wr + rt * 16 + q * 4 + r;
            if (grow < Nn) {
                ushort* drow = h2 + (size_t)grow * 256 + n0;
#pragma unroll
                for (int ct = 0; ct < 8; ++ct)
                    drow[ct * 16 + lm] = f2b(acc[rt][ct][r]);
            }
        }
    __syncthreads();
    atomicAdd(&stats2[(tid < 128 ? 0 : 256) + n0 + (tid & 127)], sRed[tid]);
}

// ---------------- GEMM3: relu(BN2(h2)) x Wl + bl -> out ----------------
__global__ __launch_bounds__(256) void k_gemm3(
    const ushort* __restrict__ h2, const float* __restrict__ ss2,
    const ushort* __restrict__ Wlt, const float* __restrict__ bl,
    float* __restrict__ out, int Nn)
{
    __shared__ ushort sA[128][72];
    __shared__ ushort sB[128][72];
    const int tid = threadIdx.x;
    const int m0 = blockIdx.x * 128;
    const int lane = tid & 63, wave = tid >> 6;
    const int q = lane >> 4, lm = lane & 15;
    const int wr = wave * 32;
    const int rs = tid >> 1;
    const int kh = (tid & 1) * 32;
    const int row = m0 + rs;
    const bool valid = row < Nn;

    floatx4 acc[2][8];
#pragma unroll
    for (int a = 0; a < 2; ++a)
#pragma unroll
        for (int b = 0; b < 8; ++b) acc[a][b] = (floatx4){0.f, 0.f, 0.f, 0.f};

#pragma unroll
    for (int kc = 0; kc < 4; ++kc) {
        const int kb = kc * 64 + kh;
        uint4* dstA = (uint4*)&sA[rs][kh];
#pragma unroll
        for (int j = 0; j < 4; ++j) {
            uint4 o = {0u, 0u, 0u, 0u};
            if (valid) {
                uint4 vv = ((const uint4*)(h2 + (size_t)row * 256 + kb))[j];
                uint wds[4] = {vv.x, vv.y, vv.z, vv.w};
                uint res[4];
#pragma unroll
                for (int p = 0; p < 4; ++p) {
                    int k0 = kb + j * 8 + p * 2;
                    float f0 = fmaxf(fmaf(b2f((ushort)(wds[p] & 0xFFFFu)), ss2[k0], ss2[256 + k0]), 0.f);
                    float f1 = fmaxf(fmaf(b2f((ushort)(wds[p] >> 16)), ss2[k0 + 1], ss2[256 + k0 + 1]), 0.f);
                    res[p] = pack2(f0, f1);
                }
                o.x = res[0]; o.y = res[1]; o.z = res[2]; o.w = res[3];
            }
            dstA[j] = o;
        }
        {
            const uint4* src = (const uint4*)(Wlt + (size_t)rs * 256 + kc * 64 + kh);
            uint4* dstB = (uint4*)&sB[rs][kh];
#pragma unroll
            for (int j = 0; j < 4; ++j) dstB[j] = src[j];
        }
        __syncthreads();
#pragma unroll
        for (int ks = 0; ks < 2; ++ks) {
            short8 a0 = *(const short8*)&sA[wr + lm][ks * 32 + q * 8];
            short8 a1 = *(const short8*)&sA[wr + 16 + lm][ks * 32 + q * 8];
#pragma unroll
            for (int ct = 0; ct < 8; ++ct) {
                short8 b = *(const short8*)&sB[ct * 16 + lm][ks * 32 + q * 8];
                acc[0][ct] = __builtin_amdgcn_mfma_f32_16x16x32_bf16(a0, b, acc[0][ct], 0, 0, 0);
                acc[1][ct] = __builtin_amdgcn_mfma_f32_16x16x32_bf16(a1, b, acc[1][ct], 0, 0, 0);
            }
        }
        __syncthreads();
    }

    float bias[8];
#pragma unroll
    for (int ct = 0; ct < 8; ++ct) bias[ct] = bl[ct * 16 + lm];
#pragma unroll
    for (int rt = 0; rt < 2; ++rt)
#pragma unroll
        for (int r = 0; r < 4; ++r) {
            int grow = m0 + wr + rt * 16 + q * 4 + r;
            if (grow < Nn) {
                float* drow = out + (size_t)grow * 128;
#pragma unroll
                for (int ct = 0; ct < 8; ++ct)
                    drow[ct * 16 + lm] = fmaxf(acc[rt][ct][r] + bias[ct], 0.f);
            }
        }
}

extern "C" void kernel_launch(void* const* d_in, const int* in_sizes, int n_in,
                              void* d_out, int out_size, void* d_ws, size_t ws_size,
                              hipStream_t stream) {
    const float* x   = (const float*)d_in[0];
    const int* eidx  = (const int*)d_in[1];
    const float* ea  = (const float*)d_in[2];
    const float* W1  = (const float*)d_in[5];
    const float* g1  = (const float*)d_in[7];
    const float* be1 = (const float*)d_in[8];
    const float* W2  = (const float*)d_in[9];
    const float* g2  = (const float*)d_in[11];
    const float* be2 = (const float*)d_in[12];
    const float* Wl  = (const float*)d_in[13];
    const float* bl  = (const float*)d_in[14];

    const int Nn = in_sizes[0] / 128;   // 50000
    const int E  = in_sizes[1] / 2;     // 1600000
    const int NB = (Nn + 255) / 256;    // 196
    const int NT = (E + 127) / 128;     // 12500

    char* w = (char*)d_ws;
    // ---- zero region ----
    float* s_acc   = (float*)w;  w += (size_t)Nn * 128 * 4;
    int*   deg     = (int*)w;    w += (size_t)Nn * 4;
    int*   fill    = (int*)w;    w += (size_t)Nn * 4;
    float* stats1B = (float*)w;  w += (size_t)128 * 256 * 4;
    float* stats2  = (float*)w;  w += 512 * 4;
    size_t zbytes = (size_t)(w - (char*)d_ws);
    // ---- fully-overwritten region ----
    float* ss1    = (float*)w;  w += 256 * 4;
    float* ss2    = (float*)w;  w += 512 * 4;
    ushort* W1t   = (ushort*)w; w += 128 * 192 * 2;
    ushort* W2t   = (ushort*)w; w += 256 * 256 * 2;
    ushort* Wlt   = (ushort*)w; w += 128 * 256 * 2;
    ushort* xb    = (ushort*)w; w += (size_t)Nn * 128 * 2;
    ushort* h2    = (ushort*)w; w += (size_t)Nn * 256 * 2;
    int*   base   = (int*)w;    w += (size_t)Nn * 4;
    int*   bsum   = (int*)w;    w += (size_t)NB * 4;
    int*   bbase  = (int*)w;    w += (size_t)NB * 4;
    int*   perm   = (int*)w;    w += (size_t)E * 4;
    int*   srcs_s = (int*)w;    w += (size_t)E * 4;
    int*   dsts_s = (int*)w;    w += (size_t)E * 4;
    ushort* xab   = (ushort*)w; w += (size_t)Nn * 128 * 2;
    float* xa     = (float*)w;  w += (size_t)Nn * 128 * 4;
    size_t need_fb = (size_t)(w - (char*)d_ws);
    ushort* h_s   = (ushort*)w; w += (size_t)E * 128 * 2;
    size_t need_main = (size_t)(w - (char*)d_ws);
    (void)n_in; (void)out_size;

    const bool main_path = (ws_size >= need_main);

    hipMemsetAsync(d_ws, 0, zbytes, stream);

    const int GS = 2048;

    k_prep_w<<<(192 * 128 + 255) / 256, 256, 0, stream>>>(W1, W1t, 192, 128);
    k_prep_w<<<(256 * 256 + 255) / 256, 256, 0, stream>>>(W2, W2t, 256, 256);
    k_prep_w<<<(256 * 128 + 255) / 256, 256, 0, stream>>>(Wl, Wlt, 256, 128);
    k_prep_x<<<GS, 256, 0, stream>>>(x, xb, Nn * 128 / 4);

    // sort edges by dst
    k_hist<<<GS, 256, 0, stream>>>(eidx + E, deg, E);
    k_bsum<<<NB, 256, 0, stream>>>(deg, bsum, Nn);
    k_bscan<<<1, 256, 0, stream>>>(bsum, bbase, NB);
    k_base<<<NB, 256, 0, stream>>>(deg, bbase, base, Nn);
    k_scatter<<<GS, 256, 0, stream>>>(eidx, base, fill, perm,
                                      main_path ? srcs_s : nullptr,
                                      main_path ? dsts_s : nullptr, E);

    if (main_path) {
        k_xa<true><<<(Nn + 127) / 128, 256, 0, stream>>>(xb, W1t, (void*)xab, Nn);
        k_edgeA<<<GS, 256, 0, stream>>>(ea, perm, srcs_s, W1t, xab, stats1B, h_s, E, NT);
        k_fin1<<<1, 128, 0, stream>>>(stats1B, g1, be1, ss1, 1.0f / (float)E);
        k_edgeB<<<GS, 256, 0, stream>>>(h_s, dsts_s, ss1, s_acc, E, NT);
    } else {
        (void)need_fb;
        k_xa<false><<<(Nn + 127) / 128, 256, 0, stream>>>(xb, W1t, (void*)xa, Nn);
        k_edge1<<<GS, 256, 0, stream>>>(ea, eidx, W1t, xa, stats1B, E, NT);
        k_fin1<<<1, 128, 0, stream>>>(stats1B, g1, be1, ss1, 1.0f / (float)E);
        k_edge2<<<GS, 256, 0, stream>>>(ea, eidx, perm, W1t, xa, ss1, s_acc, E, NT);
    }

    dim3 grid2((Nn + 127) / 128, 2);
    k_gemm2<<<grid2, 256, 0, stream>>>(xb, s_acc, deg, W2t, stats2, h2, Nn);
    k_fin<<<1, 256, 0, stream>>>(stats2, g2, be2, ss2, 256, 1.0f / (float)Nn);
    k_gemm3<<<(Nn + 127) / 128, 256, 0, stream>>>(h2, ss2, Wlt, bl, (float*)d_out, Nn);
}

// Round 3
// 1181.615 us; speedup vs baseline: 1.3268x; 1.1235x over previous
//
#include <hip/hip_runtime.h>
#include <stdint.h>

#define EPSV 1e-5f

typedef short short8 __attribute__((ext_vector_type(8)));
typedef float floatx4 __attribute__((ext_vector_type(4)));

static __device__ __forceinline__ ushort f2b(float f) {
    union { float f; uint32_t u; } v; v.f = f;
    return (ushort)((v.u + 0x7FFFu + ((v.u >> 16) & 1u)) >> 16);
}
static __device__ __forceinline__ uint pack2(float a, float b) {
    return (uint)f2b(a) | ((uint)f2b(b) << 16);
}
static __device__ __forceinline__ float b2f(ushort b) {
    union { uint32_t u; float f; } v; v.u = ((uint32_t)b) << 16;
    return v.f;
}

// ---------------- prep kernels ----------------
// Permuted weight transpose: row r of Wt holds W column perm(r), where within
// each 128-col half: r = (m&7)*16 + (m>>3)  <=>  true col m = (r&15)*8 + (r>>4).
// Makes a thread's 8 MFMA fragment cols (ct=0..7, fixed lm) CONSECUTIVE true cols.
__global__ void k_prep_wp(const float* __restrict__ W, ushort* __restrict__ Wt,
                          int K, int Nc) {
    int i = blockIdx.x * blockDim.x + threadIdx.x;
    if (i >= K * Nc) return;
    int n = i % Nc, k = i / Nc;
    int m = n & 127;
    int r = (n & ~127) + (m & 7) * 16 + (m >> 3);
    Wt[(size_t)r * K + k] = f2b(W[i]);
}

__global__ void k_prep_x(const float* __restrict__ x, ushort* __restrict__ xb, int n4) {
    int stride = gridDim.x * blockDim.x;
    for (int i = blockIdx.x * blockDim.x + threadIdx.x; i < n4; i += stride) {
        float4 v = ((const float4*)x)[i];
        uint2 o; o.x = pack2(v.x, v.y); o.y = pack2(v.z, v.w);
        ((uint2*)xb)[i] = o;
    }
}

// ---------------- sort-by-dst pipeline ----------------
__global__ void k_hist(const int* __restrict__ col, int* __restrict__ deg, int E) {
    int stride = gridDim.x * blockDim.x;
    for (int i = blockIdx.x * blockDim.x + threadIdx.x; i < E; i += stride)
        atomicAdd(&deg[col[i]], 1);
}

__global__ void k_bsum(const int* __restrict__ deg, int* __restrict__ bsum, int Nn) {
    __shared__ int red[256];
    int t = threadIdx.x;
    int i = blockIdx.x * 256 + t;
    red[t] = (i < Nn) ? deg[i] : 0;
    __syncthreads();
    for (int s = 128; s > 0; s >>= 1) {
        if (t < s) red[t] += red[t + s];
        __syncthreads();
    }
    if (t == 0) bsum[blockIdx.x] = red[0];
}

__global__ void k_bscan(const int* __restrict__ bsum, int* __restrict__ bbase, int NB) {
    __shared__ int s[256];
    int t = threadIdx.x;
    int v = (t < NB) ? bsum[t] : 0;
    s[t] = v;
    __syncthreads();
    for (int off = 1; off < 256; off <<= 1) {
        int u = (t >= off) ? s[t - off] : 0;
        __syncthreads();
        s[t] += u;
        __syncthreads();
    }
    if (t < NB) bbase[t] = s[t] - v;
}

__global__ void k_base(const int* __restrict__ deg, const int* __restrict__ bbase,
                       int* __restrict__ base, int Nn) {
    __shared__ int s[256];
    int t = threadIdx.x;
    int i = blockIdx.x * 256 + t;
    int v = (i < Nn) ? deg[i] : 0;
    s[t] = v;
    __syncthreads();
    for (int off = 1; off < 256; off <<= 1) {
        int u = (t >= off) ? s[t - off] : 0;
        __syncthreads();
        s[t] += u;
        __syncthreads();
    }
    if (i < Nn) base[i] = bbase[blockIdx.x] + s[t] - v;
}

__global__ void k_scatter(const int* __restrict__ eidx, const int* __restrict__ base,
                          int* __restrict__ fill, int* __restrict__ perm,
                          int* __restrict__ srcs, int* __restrict__ dsts, int E) {
    int stride = gridDim.x * blockDim.x;
    for (int e = blockIdx.x * blockDim.x + threadIdx.x; e < E; e += stride) {
        int d = eidx[E + e];
        int pos = base[d] + atomicAdd(&fill[d], 1);
        perm[pos] = e;
        if (srcs) { srcs[pos] = eidx[e]; dsts[pos] = d; }
    }
}

// stats [2][C] (sum, sumsq) -> ss [2][C] (scale, shift)
__global__ void k_fin(const float* __restrict__ stats, const float* __restrict__ g,
                      const float* __restrict__ be, float* __restrict__ ss,
                      int C, float invM) {
    int c = blockIdx.x * blockDim.x + threadIdx.x;
    if (c >= C) return;
    float mean = stats[c] * invM;
    float var  = stats[C + c] * invM - mean * mean;
    float scale = g[c] * rsqrtf(var + EPSV);
    ss[c] = scale;
    ss[C + c] = be[c] - mean * scale;
}

__global__ void k_fin1(const float* __restrict__ statsB, const float* __restrict__ g,
                       const float* __restrict__ be, float* __restrict__ ss, float invM) {
    int c = threadIdx.x;   // 128 threads
    float sm = 0.f, sq = 0.f;
    for (int b = 0; b < 128; ++b) {
        sm += statsB[b * 256 + c];
        sq += statsB[b * 256 + 128 + c];
    }
    float mean = sm * invM;
    float var  = sq * invM - mean * mean;
    float scale = g[c] * rsqrtf(var + EPSV);
    ss[c] = scale;
    ss[128 + c] = be[c] - mean * scale;
}

// ---------------- k_xa: xa = x @ W1[:128,:]  (fp32 or bf16 out, std layout) ----------------
template <bool BF>
__global__ __launch_bounds__(256) void k_xa(
    const ushort* __restrict__ xb, const ushort* __restrict__ W1t,
    void* __restrict__ out, int Nn)
{
    __shared__ ushort sA[128][72];
    __shared__ ushort sB[128][72];
    const int tid = threadIdx.x;
    const int lane = tid & 63, wave = tid >> 6;
    const int q = lane >> 4, lm = lane & 15;
    const int wr = wave * 32;
    const int rs = tid >> 1;
    const int kh = (tid & 1) * 32;
    const int m0 = blockIdx.x * 128;
    const int row = m0 + rs;
    const bool valid = row < Nn;

    floatx4 acc[2][8];
#pragma unroll
    for (int a = 0; a < 2; ++a)
#pragma unroll
        for (int b = 0; b < 8; ++b) acc[a][b] = (floatx4){0.f, 0.f, 0.f, 0.f};

#pragma unroll
    for (int kc = 0; kc < 2; ++kc) {
        uint4* dstA = (uint4*)&sA[rs][kh];
        const uint4* srcA = (const uint4*)(xb + (size_t)row * 128 + kc * 64 + kh);
#pragma unroll
        for (int j = 0; j < 4; ++j) {
            uint4 o = {0u, 0u, 0u, 0u};
            if (valid) o = srcA[j];
            dstA[j] = o;
        }
        const uint4* srcB = (const uint4*)(W1t + (size_t)rs * 192 + kc * 64 + kh);
        uint4* dstB = (uint4*)&sB[rs][kh];
#pragma unroll
        for (int j = 0; j < 4; ++j) dstB[j] = srcB[j];
        __syncthreads();
#pragma unroll
        for (int ks = 0; ks < 2; ++ks) {
            short8 a0 = *(const short8*)&sA[wr + lm][ks * 32 + q * 8];
            short8 a1 = *(const short8*)&sA[wr + 16 + lm][ks * 32 + q * 8];
#pragma unroll
            for (int ct = 0; ct < 8; ++ct) {
                short8 b = *(const short8*)&sB[ct * 16 + lm][ks * 32 + q * 8];
                acc[0][ct] = __builtin_amdgcn_mfma_f32_16x16x32_bf16(a0, b, acc[0][ct], 0, 0, 0);
                acc[1][ct] = __builtin_amdgcn_mfma_f32_16x16x32_bf16(a1, b, acc[1][ct], 0, 0, 0);
            }
        }
        __syncthreads();
    }
    // permuted fragments: acc[rt][ct][r] = true col lm*8+ct -> vector stores
#pragma unroll
    for (int rt = 0; rt < 2; ++rt)
#pragma unroll
        for (int r = 0; r < 4; ++r) {
            int grow = m0 + wr + rt * 16 + q * 4 + r;
            if (grow < Nn) {
                if (BF) {
                    uint4 o;
                    o.x = pack2(acc[rt][0][r], acc[rt][1][r]);
                    o.y = pack2(acc[rt][2][r], acc[rt][3][r]);
                    o.z = pack2(acc[rt][4][r], acc[rt][5][r]);
                    o.w = pack2(acc[rt][6][r], acc[rt][7][r]);
                    ((uint4*)((ushort*)out + (size_t)grow * 128))[lm] = o;
                } else {
                    float* drow = (float*)out + (size_t)grow * 128 + lm * 8;
                    float4 f0 = {acc[rt][0][r], acc[rt][1][r], acc[rt][2][r], acc[rt][3][r]};
                    float4 f1 = {acc[rt][4][r], acc[rt][5][r], acc[rt][6][r], acc[rt][7][r]};
                    ((float4*)drow)[0] = f0;
                    ((float4*)drow)[1] = f1;
                }
            }
        }
}

// ============ MAIN PATH ============
// k_edgeA: dst-sorted single compute pass. t = ea@W1e (K=64, MFMA, W1e resident
// in LDS), h = t + xab[src] via DIRECT coalesced uint4 register gather
// (permuted fragments = 8 consecutive true cols/thread), register BN stats,
// coalesced uint4 h store. 2 barriers/tile.
__global__ __launch_bounds__(256) void k_edgeA(
    const float* __restrict__ ea, const int* __restrict__ perm,
    const int* __restrict__ srcs, const ushort* __restrict__ W1t,
    const ushort* __restrict__ xab, float* __restrict__ statsB,
    ushort* __restrict__ hs, int E, int NT)
{
    __shared__ ushort sA[128][72];
    __shared__ ushort sB[128][72];
    __shared__ int sSrc[128];
    __shared__ float sRed[256];

    const int tid = threadIdx.x;
    const int lane = tid & 63, wave = tid >> 6;
    const int q = lane >> 4, lm = lane & 15;
    const int wr = wave * 32;
    const int rs = tid >> 1;
    const int kh = (tid & 1) * 32;

    {   // W1e resident: rows n=0..127, k=128..191
        const uint4* srcB = (const uint4*)(W1t + (size_t)rs * 192 + 128 + kh);
        uint4* dstB = (uint4*)&sB[rs][kh];
#pragma unroll
        for (int j = 0; j < 4; ++j) dstB[j] = srcB[j];
    }

    float s1[8], s2[8];
#pragma unroll
    for (int ct = 0; ct < 8; ++ct) { s1[ct] = 0.f; s2[ct] = 0.f; }

    for (int tile = blockIdx.x; tile < NT; tile += gridDim.x) {
        const int e0 = tile * 128;
        __syncthreads();   // prev tile's sA/sSrc readers done; sB visible (1st iter)
        if (tid < 128) {
            int e = e0 + tid;
            sSrc[tid] = (e < E) ? srcs[e] : -1;
        }
        {   // stage A: ea gathered via perm (fp32 -> bf16)
            int e = e0 + rs;
            int pe = (e < E) ? perm[e] : -1;
            const float4* srcA = (const float4*)(ea + (size_t)pe * 64 + kh);
            uint4* dstA = (uint4*)&sA[rs][kh];
#pragma unroll
            for (int j = 0; j < 4; ++j) {
                uint4 o = {0u, 0u, 0u, 0u};
                if (pe >= 0) {
                    float4 v0 = srcA[2 * j], v1 = srcA[2 * j + 1];
                    o.x = pack2(v0.x, v0.y); o.y = pack2(v0.z, v0.w);
                    o.z = pack2(v1.x, v1.y); o.w = pack2(v1.z, v1.w);
                }
                dstA[j] = o;
            }
        }
        __syncthreads();

        floatx4 acc[2][8];
#pragma unroll
        for (int a = 0; a < 2; ++a)
#pragma unroll
            for (int b = 0; b < 8; ++b) acc[a][b] = (floatx4){0.f, 0.f, 0.f, 0.f};
#pragma unroll
        for (int ks = 0; ks < 2; ++ks) {
            short8 a0 = *(const short8*)&sA[wr + lm][ks * 32 + q * 8];
            short8 a1 = *(const short8*)&sA[wr + 16 + lm][ks * 32 + q * 8];
#pragma unroll
            for (int ct = 0; ct < 8; ++ct) {
                short8 b = *(const short8*)&sB[ct * 16 + lm][ks * 32 + q * 8];
                acc[0][ct] = __builtin_amdgcn_mfma_f32_16x16x32_bf16(a0, b, acc[0][ct], 0, 0, 0);
                acc[1][ct] = __builtin_amdgcn_mfma_f32_16x16x32_bf16(a1, b, acc[1][ct], 0, 0, 0);
            }
        }
        // epilogue: per row, 1 uint4 xab gather + add + stats + 1 uint4 h store.
        // 16 lanes of a quarter (fixed q => fixed trow) cover one 256B row.
#pragma unroll
        for (int rt = 0; rt < 2; ++rt)
#pragma unroll
            for (int r = 0; r < 4; ++r) {
                int trow = wr + rt * 16 + q * 4 + r;
                int srcn = sSrc[trow];
                if (srcn >= 0) {
                    uint4 g = ((const uint4*)(xab + (size_t)srcn * 128))[lm];
                    uint gw[4] = {g.x, g.y, g.z, g.w};
                    float hv[8];
#pragma unroll
                    for (int ct = 0; ct < 8; ++ct) {
                        ushort gb = (ushort)(gw[ct >> 1] >> ((ct & 1) * 16));
                        float v = acc[rt][ct][r] + b2f(gb);
                        s1[ct] += v; s2[ct] += v * v;
                        hv[ct] = v;
                    }
                    uint4 o;
                    o.x = pack2(hv[0], hv[1]); o.y = pack2(hv[2], hv[3]);
                    o.z = pack2(hv[4], hv[5]); o.w = pack2(hv[6], hv[7]);
                    ((uint4*)(hs + (size_t)(e0 + trow) * 128))[lm] = o;
                }
            }
    }

    __syncthreads();
    sRed[tid] = 0.f;
    __syncthreads();
#pragma unroll
    for (int ct = 0; ct < 8; ++ct) {
        float sm2 = s1[ct], sq2 = s2[ct];
        sm2 += __shfl_xor(sm2, 16, 64); sm2 += __shfl_xor(sm2, 32, 64);
        sq2 += __shfl_xor(sq2, 16, 64); sq2 += __shfl_xor(sq2, 32, 64);
        if (q == 0) {
            atomicAdd(&sRed[lm * 8 + ct], sm2);
            atomicAdd(&sRed[128 + lm * 8 + ct], sq2);
        }
    }
    __syncthreads();
    atomicAdd(&statsB[(size_t)(blockIdx.x & 127) * 256 + tid], sRed[tid]);
}

// k_edgeB: stream sorted h (uint loads, 2 cols/thread), BN+relu,
// run-length segmented reduce by dst -> sacc
__global__ __launch_bounds__(256) void k_edgeB(
    const ushort* __restrict__ hs, const int* __restrict__ dsts,
    const float* __restrict__ ss, float* __restrict__ sacc, int E, int NT)
{
    __shared__ int sDst[128];
    const int tid = threadIdx.x;
    const int c0 = (tid & 63) * 2;
    const int chunk = tid >> 6;          // 4 chunks x 32 rows
    const float sc0 = ss[c0],     sh0 = ss[128 + c0];
    const float sc1 = ss[c0 + 1], sh1 = ss[128 + c0 + 1];

    for (int tile = blockIdx.x; tile < NT; tile += gridDim.x) {
        const int e0 = tile * 128;
        __syncthreads();
        if (tid < 128) {
            int e = e0 + tid;
            sDst[tid] = (e < E) ? dsts[e] : -1;
        }
        __syncthreads();
        const int rbeg = chunk * 32;
        int cur = sDst[rbeg];
        float r0 = 0.f, r1 = 0.f;
#pragma unroll 4
        for (int i = 0; i < 32; ++i) {
            int d = sDst[rbeg + i];
            float v0 = 0.f, v1 = 0.f;
            if (d >= 0) {
                uint hv = *(const uint*)(hs + (size_t)(e0 + rbeg + i) * 128 + c0);
                v0 = fmaxf(fmaf(b2f((ushort)(hv & 0xFFFFu)), sc0, sh0), 0.f);
                v1 = fmaxf(fmaf(b2f((ushort)(hv >> 16)), sc1, sh1), 0.f);
            }
            if (d != cur) {
                if (cur >= 0) {
                    atomicAdd(&sacc[(size_t)cur * 128 + c0], r0);
                    atomicAdd(&sacc[(size_t)cur * 128 + c0 + 1], r1);
                }
                r0 = 0.f; r1 = 0.f; cur = d;
            }
            r0 += v0; r1 += v1;
        }
        if (cur >= 0) {
            atomicAdd(&sacc[(size_t)cur * 128 + c0], r0);
            atomicAdd(&sacc[(size_t)cur * 128 + c0 + 1], r1);
        }
    }
}

// ============ FALLBACK PATH (only if ws too small; permuted-layout aware) ============
__global__ __launch_bounds__(256) void k_edge1(
    const float* __restrict__ ea, const int* __restrict__ eidx,
    const ushort* __restrict__ W1t, const float* __restrict__ xa,
    float* __restrict__ statsB, int E, int NT)
{
    __shared__ ushort sA[128][72];
    __shared__ ushort sB[128][72];
    __shared__ int sSrc[128];
    __shared__ float sRed[256];

    const int tid = threadIdx.x;
    const int lane = tid & 63, wave = tid >> 6;
    const int q = lane >> 4, lm = lane & 15;
    const int wr = wave * 32;
    const int rs = tid >> 1;
    const int kh = (tid & 1) * 32;

    {
        const uint4* srcB = (const uint4*)(W1t + (size_t)rs * 192 + 128 + kh);
        uint4* dstB = (uint4*)&sB[rs][kh];
#pragma unroll
        for (int j = 0; j < 4; ++j) dstB[j] = srcB[j];
    }

    float s1[8], s2[8];
#pragma unroll
    for (int ct = 0; ct < 8; ++ct) { s1[ct] = 0.f; s2[ct] = 0.f; }

    for (int tile = blockIdx.x; tile < NT; tile += gridDim.x) {
        const int e0 = tile * 128;
        __syncthreads();
        if (tid < 128) {
            int e = e0 + tid;
            sSrc[tid] = (e < E) ? eidx[e] : -1;
        }
        {
            const bool valid = (e0 + rs) < E;
            const float4* srcA = (const float4*)(ea + (size_t)(e0 + rs) * 64 + kh);
            uint4* dstA = (uint4*)&sA[rs][kh];
#pragma unroll
            for (int j = 0; j < 4; ++j) {
                uint4 o = {0u, 0u, 0u, 0u};
                if (valid) {
                    float4 v0 = srcA[2 * j], v1 = srcA[2 * j + 1];
                    o.x = pack2(v0.x, v0.y); o.y = pack2(v0.z, v0.w);
                    o.z = pack2(v1.x, v1.y); o.w = pack2(v1.z, v1.w);
                }
                dstA[j] = o;
            }
        }
        __syncthreads();

        floatx4 acc[2][8];
#pragma unroll
        for (int a = 0; a < 2; ++a)
#pragma unroll
            for (int b = 0; b < 8; ++b) acc[a][b] = (floatx4){0.f, 0.f, 0.f, 0.f};
#pragma unroll
        for (int ks = 0; ks < 2; ++ks) {
            short8 a0 = *(const short8*)&sA[wr + lm][ks * 32 + q * 8];
            short8 a1 = *(const short8*)&sA[wr + 16 + lm][ks * 32 + q * 8];
#pragma unroll
            for (int ct = 0; ct < 8; ++ct) {
                short8 b = *(const short8*)&sB[ct * 16 + lm][ks * 32 + q * 8];
                acc[0][ct] = __builtin_amdgcn_mfma_f32_16x16x32_bf16(a0, b, acc[0][ct], 0, 0, 0);
                acc[1][ct] = __builtin_amdgcn_mfma_f32_16x16x32_bf16(a1, b, acc[1][ct], 0, 0, 0);
            }
        }
#pragma unroll
        for (int rt = 0; rt < 2; ++rt)
#pragma unroll
            for (int r = 0; r < 4; ++r) {
                int trow = wr + rt * 16 + q * 4 + r;
                int srcn = sSrc[trow];
                if (srcn >= 0) {
                    const float* xr = xa + (size_t)srcn * 128 + lm * 8;
#pragma unroll
                    for (int ct = 0; ct < 8; ++ct) {
                        float v = acc[rt][ct][r] + xr[ct];
                        s1[ct] += v; s2[ct] += v * v;
                    }
                }
            }
    }

    __syncthreads();
    sRed[tid] = 0.f;
    __syncthreads();
#pragma unroll
    for (int ct = 0; ct < 8; ++ct) {
        float sm = s1[ct], sq = s2[ct];
        sm += __shfl_xor(sm, 16, 64); sm += __shfl_xor(sm, 32, 64);
        sq += __shfl_xor(sq, 16, 64); sq += __shfl_xor(sq, 32, 64);
        if (q == 0) {
            atomicAdd(&sRed[lm * 8 + ct], sm);
            atomicAdd(&sRed[128 + lm * 8 + ct], sq);
        }
    }
    __syncthreads();
    atomicAdd(&statsB[(size_t)(blockIdx.x & 127) * 256 + tid], sRed[tid]);
}

__global__ __launch_bounds__(256) void k_edge2(
    const float* __restrict__ ea, const int* __restrict__ eidx,
    const int* __restrict__ perm, const ushort* __restrict__ W1t,
    const float* __restrict__ xa, const float* __restrict__ ss,
    float* __restrict__ sacc, int E, int NT)
{
    __shared__ union SM {
        struct { ushort A[128][72]; ushort B[128][72]; } t;
        float buf[64][132];
    } sm;
    __shared__ int sSrc[128];
    __shared__ int sDst[128];

    const int tid = threadIdx.x;
    const int lane = tid & 63, wave = tid >> 6;
    const int q = lane >> 4, lm = lane & 15;
    const int wr = wave * 32;
    const int rs = tid >> 1;
    const int kh = (tid & 1) * 32;

    float sc[8], sh[8];
#pragma unroll
    for (int ct = 0; ct < 8; ++ct) {
        sc[ct] = ss[lm * 8 + ct];
        sh[ct] = ss[128 + lm * 8 + ct];
    }

    for (int tile = blockIdx.x; tile < NT; tile += gridDim.x) {
        const int e0 = tile * 128;
        __syncthreads();
        if (tid < 128) {
            int e = e0 + tid;
            int pe = (e < E) ? perm[e] : -1;
            sSrc[tid] = (pe >= 0) ? eidx[pe] : -1;
            sDst[tid] = (pe >= 0) ? eidx[E + pe] : -1;
        }
        {
            int e = e0 + rs;
            int pe = (e < E) ? perm[e] : -1;
            const float4* srcA = (const float4*)(ea + (size_t)pe * 64 + kh);
            uint4* dstA = (uint4*)&sm.t.A[rs][kh];
#pragma unroll
            for (int j = 0; j < 4; ++j) {
                uint4 o = {0u, 0u, 0u, 0u};
                if (pe >= 0) {
                    float4 v0 = srcA[2 * j], v1 = srcA[2 * j + 1];
                    o.x = pack2(v0.x, v0.y); o.y = pack2(v0.z, v0.w);
                    o.z = pack2(v1.x, v1.y); o.w = pack2(v1.z, v1.w);
                }
                dstA[j] = o;
            }
            const uint4* srcB = (const uint4*)(W1t + (size_t)rs * 192 + 128 + kh);
            uint4* dstB = (uint4*)&sm.t.B[rs][kh];
#pragma unroll
            for (int j = 0; j < 4; ++j) dstB[j] = srcB[j];
        }
        __syncthreads();

        floatx4 acc[2][8];
#pragma unroll
        for (int a = 0; a < 2; ++a)
#pragma unroll
            for (int b = 0; b < 8; ++b) acc[a][b] = (floatx4){0.f, 0.f, 0.f, 0.f};
#pragma unroll
        for (int ks = 0; ks < 2; ++ks) {
            short8 a0 = *(const short8*)&sm.t.A[wr + lm][ks * 32 + q * 8];
            short8 a1 = *(const short8*)&sm.t.A[wr + 16 + lm][ks * 32 + q * 8];
#pragma unroll
            for (int ct = 0; ct < 8; ++ct) {
                short8 b = *(const short8*)&sm.t.B[ct * 16 + lm][ks * 32 + q * 8];
                acc[0][ct] = __builtin_amdgcn_mfma_f32_16x16x32_bf16(a0, b, acc[0][ct], 0, 0, 0);
                acc[1][ct] = __builtin_amdgcn_mfma_f32_16x16x32_bf16(a1, b, acc[1][ct], 0, 0, 0);
            }
        }
#pragma unroll
        for (int rt = 0; rt < 2; ++rt)
#pragma unroll
            for (int r = 0; r < 4; ++r) {
                int trow = wr + rt * 16 + q * 4 + r;
                int srcn = sSrc[trow];
                if (srcn >= 0) {
                    const float* xr = xa + (size_t)srcn * 128 + lm * 8;
#pragma unroll
                    for (int ct = 0; ct < 8; ++ct)
                        acc[rt][ct][r] += xr[ct];
                }
            }

#pragma unroll
        for (int half = 0; half < 2; ++half) {
            __syncthreads();
            if ((wave >> 1) == half) {
                int rb = (wave & 1) * 32;
#pragma unroll
                for (int rt = 0; rt < 2; ++rt)
#pragma unroll
                    for (int r = 0; r < 4; ++r) {
                        int rowl = rb + rt * 16 + q * 4 + r;
#pragma unroll
                        for (int ct = 0; ct < 8; ++ct) {
                            float v = fmaxf(fmaf(acc[rt][ct][r], sc[ct], sh[ct]), 0.f);
                            sm.buf[rowl][lm * 8 + ct] = v;
                        }
                    }
            }
            __syncthreads();
            int c = tid & 127, chunk = tid >> 7;
            int rbeg = half * 64 + chunk * 32;
            int cur = sDst[rbeg];
            float run = 0.f;
#pragma unroll 4
            for (int i = 0; i < 32; ++i) {
                int d = sDst[rbeg + i];
                float v = sm.buf[chunk * 32 + i][c];
                if (d != cur) {
                    if (cur >= 0) atomicAdd(&sacc[(size_t)cur * 128 + c], run);
                    run = 0.f; cur = d;
                }
                run += v;
            }
            if (cur >= 0) atomicAdd(&sacc[(size_t)cur * 128 + c], run);
        }
    }
}

// ---------------- GEMM2: [N,256] x [256,256] (+stats2, h2 bf16 out) ----------------
__global__ __launch_bounds__(256) void k_gemm2(
    const ushort* __restrict__ xb, const float* __restrict__ sacc,
    const int* __restrict__ deg, const ushort* __restrict__ W2t,
    float* __restrict__ stats2, ushort* __restrict__ h2, int Nn)
{
    __shared__ ushort sA[128][72];
    __shared__ ushort sB[128][72];
    __shared__ float sRed[256];

    const int tid = threadIdx.x;
    const int m0 = blockIdx.x * 128;
    const int n0 = blockIdx.y * 128;
    const int lane = tid & 63, wave = tid >> 6;
    const int q = lane >> 4, lm = lane & 15;
    const int wr = wave * 32;
    const int rs = tid >> 1;
    const int kh = (tid & 1) * 32;
    const int row = m0 + rs;
    const bool valid = row < Nn;
    float inv = 0.f;
    if (valid) {
        int d = deg[row];
        inv = (d > 0) ? 1.f / (float)d : 0.f;
    }

    floatx4 acc[2][8];
#pragma unroll
    for (int a = 0; a < 2; ++a)
#pragma unroll
        for (int b = 0; b < 8; ++b) acc[a][b] = (floatx4){0.f, 0.f, 0.f, 0.f};

#pragma unroll
    for (int kc = 0; kc < 4; ++kc) {
        uint4* dstA = (uint4*)&sA[rs][kh];
        if (kc < 2) {
            const uint4* src = (const uint4*)(xb + (size_t)row * 128 + kc * 64 + kh);
#pragma unroll
            for (int j = 0; j < 4; ++j) {
                uint4 o = {0u, 0u, 0u, 0u};
                if (valid) o = src[j];
                dstA[j] = o;
            }
        } else {
            const float4* src = (const float4*)(sacc + (size_t)row * 128 + (kc - 2) * 64 + kh);
#pragma unroll
            for (int j = 0; j < 4; ++j) {
                uint4 o = {0u, 0u, 0u, 0u};
                if (valid) {
                    float4 v0 = src[2 * j], v1 = src[2 * j + 1];
                    o.x = pack2(v0.x * inv, v0.y * inv); o.y = pack2(v0.z * inv, v0.w * inv);
                    o.z = pack2(v1.x * inv, v1.y * inv); o.w = pack2(v1.z * inv, v1.w * inv);
                }
                dstA[j] = o;
            }
        }
        {
            const uint4* src = (const uint4*)(W2t + (size_t)(n0 + rs) * 256 + kc * 64 + kh);
            uint4* dstB = (uint4*)&sB[rs][kh];
#pragma unroll
            for (int j = 0; j < 4; ++j) dstB[j] = src[j];
        }
        __syncthreads();
#pragma unroll
        for (int ks = 0; ks < 2; ++ks) {
            short8 a0 = *(const short8*)&sA[wr + lm][ks * 32 + q * 8];
            short8 a1 = *(const short8*)&sA[wr + 16 + lm][ks * 32 + q * 8];
#pragma unroll
            for (int ct = 0; ct < 8; ++ct) {
                short8 b = *(const short8*)&sB[ct * 16 + lm][ks * 32 + q * 8];
                acc[0][ct] = __builtin_amdgcn_mfma_f32_16x16x32_bf16(a0, b, acc[0][ct], 0, 0, 0);
                acc[1][ct] = __builtin_amdgcn_mfma_f32_16x16x32_bf16(a1, b, acc[1][ct], 0, 0, 0);
            }
        }
        __syncthreads();
    }

    sRed[tid] = 0.f;
    __syncthreads();
#pragma unroll
    for (int ct = 0; ct < 8; ++ct) {
        float sm = 0.f, sq = 0.f;
#pragma unroll
        for (int rt = 0; rt < 2; ++rt)
#pragma unroll
            for (int r = 0; r < 4; ++r) {
                float v = acc[rt][ct][r];
                sm += v; sq += v * v;
            }
        sm += __shfl_xor(sm, 16, 64); sm += __shfl_xor(sm, 32, 64);
        sq += __shfl_xor(sq, 16, 64); sq += __shfl_xor(sq, 32, 64);
        if (q == 0) {
            atomicAdd(&sRed[lm * 8 + ct], sm);
            atomicAdd(&sRed[128 + lm * 8 + ct], sq);
        }
    }
#pragma unroll
    for (int rt = 0; rt < 2; ++rt)
#pragma unroll
        for (int r = 0; r < 4; ++r) {
            int grow = m0 + wr + rt * 16 + q * 4 + r;
            if (grow < Nn) {
                uint4 o;
                o.x = pack2(acc[rt][0][r], acc[rt][1][r]);
                o.y = pack2(acc[rt][2][r], acc[rt][3][r]);
                o.z = pack2(acc[rt][4][r], acc[rt][5][r]);
                o.w = pack2(acc[rt][6][r], acc[rt][7][r]);
                ((uint4*)(h2 + (size_t)grow * 256 + n0))[lm] = o;
            }
        }
    __syncthreads();
    atomicAdd(&stats2[(tid < 128 ? 0 : 256) + n0 + (tid & 127)], sRed[tid]);
}

// ---------------- GEMM3: relu(BN2(h2)) x Wl + bl -> out ----------------
__global__ __launch_bounds__(256) void k_gemm3(
    const ushort* __restrict__ h2, const float* __restrict__ ss2,
    const ushort* __restrict__ Wlt, const float* __restrict__ bl,
    float* __restrict__ out, int Nn)
{
    __shared__ ushort sA[128][72];
    __shared__ ushort sB[128][72];
    const int tid = threadIdx.x;
    const int m0 = blockIdx.x * 128;
    const int lane = tid & 63, wave = tid >> 6;
    const int q = lane >> 4, lm = lane & 15;
    const int wr = wave * 32;
    const int rs = tid >> 1;
    const int kh = (tid & 1) * 32;
    const int row = m0 + rs;
    const bool valid = row < Nn;

    floatx4 acc[2][8];
#pragma unroll
    for (int a = 0; a < 2; ++a)
#pragma unroll
        for (int b = 0; b < 8; ++b) acc[a][b] = (floatx4){0.f, 0.f, 0.f, 0.f};

#pragma unroll
    for (int kc = 0; kc < 4; ++kc) {
        const int kb = kc * 64 + kh;
        uint4* dstA = (uint4*)&sA[rs][kh];
#pragma unroll
        for (int j = 0; j < 4; ++j) {
            uint4 o = {0u, 0u, 0u, 0u};
            if (valid) {
                uint4 vv = ((const uint4*)(h2 + (size_t)row * 256 + kb))[j];
                uint wds[4] = {vv.x, vv.y, vv.z, vv.w};
                uint res[4];
#pragma unroll
                for (int p = 0; p < 4; ++p) {
                    int k0 = kb + j * 8 + p * 2;
                    float f0 = fmaxf(fmaf(b2f((ushort)(wds[p] & 0xFFFFu)), ss2[k0], ss2[256 + k0]), 0.f);
                    float f1 = fmaxf(fmaf(b2f((ushort)(wds[p] >> 16)), ss2[k0 + 1], ss2[256 + k0 + 1]), 0.f);
                    res[p] = pack2(f0, f1);
                }
                o.x = res[0]; o.y = res[1]; o.z = res[2]; o.w = res[3];
            }
            dstA[j] = o;
        }
        {
            const uint4* src = (const uint4*)(Wlt + (size_t)rs * 256 + kc * 64 + kh);
            uint4* dstB = (uint4*)&sB[rs][kh];
#pragma unroll
            for (int j = 0; j < 4; ++j) dstB[j] = src[j];
        }
        __syncthreads();
#pragma unroll
        for (int ks = 0; ks < 2; ++ks) {
            short8 a0 = *(const short8*)&sA[wr + lm][ks * 32 + q * 8];
            short8 a1 = *(const short8*)&sA[wr + 16 + lm][ks * 32 + q * 8];
#pragma unroll
            for (int ct = 0; ct < 8; ++ct) {
                short8 b = *(const short8*)&sB[ct * 16 + lm][ks * 32 + q * 8];
                acc[0][ct] = __builtin_amdgcn_mfma_f32_16x16x32_bf16(a0, b, acc[0][ct], 0, 0, 0);
                acc[1][ct] = __builtin_amdgcn_mfma_f32_16x16x32_bf16(a1, b, acc[1][ct], 0, 0, 0);
            }
        }
        __syncthreads();
    }

    float bias[8];
#pragma unroll
    for (int ct = 0; ct < 8; ++ct) bias[ct] = bl[lm * 8 + ct];
#pragma unroll
    for (int rt = 0; rt < 2; ++rt)
#pragma unroll
        for (int r = 0; r < 4; ++r) {
            int grow = m0 + wr + rt * 16 + q * 4 + r;
            if (grow < Nn) {
                float* drow = out + (size_t)grow * 128 + lm * 8;
                float4 f0 = {fmaxf(acc[rt][0][r] + bias[0], 0.f),
                             fmaxf(acc[rt][1][r] + bias[1], 0.f),
                             fmaxf(acc[rt][2][r] + bias[2], 0.f),
                             fmaxf(acc[rt][3][r] + bias[3], 0.f)};
                float4 f1 = {fmaxf(acc[rt][4][r] + bias[4], 0.f),
                             fmaxf(acc[rt][5][r] + bias[5], 0.f),
                             fmaxf(acc[rt][6][r] + bias[6], 0.f),
                             fmaxf(acc[rt][7][r] + bias[7], 0.f)};
                ((float4*)drow)[0] = f0;
                ((float4*)drow)[1] = f1;
            }
        }
}

extern "C" void kernel_launch(void* const* d_in, const int* in_sizes, int n_in,
                              void* d_out, int out_size, void* d_ws, size_t ws_size,
                              hipStream_t stream) {
    const float* x   = (const float*)d_in[0];
    const int* eidx  = (const int*)d_in[1];
    const float* ea  = (const float*)d_in[2];
    const float* W1  = (const float*)d_in[5];
    const float* g1  = (const float*)d_in[7];
    const float* be1 = (const float*)d_in[8];
    const float* W2  = (const float*)d_in[9];
    const float* g2  = (const float*)d_in[11];
    const float* be2 = (const float*)d_in[12];
    const float* Wl  = (const float*)d_in[13];
    const float* bl  = (const float*)d_in[14];

    const int Nn = in_sizes[0] / 128;   // 50000
    const int E  = in_sizes[1] / 2;     // 1600000
    const int NB = (Nn + 255) / 256;    // 196
    const int NT = (E + 127) / 128;     // 12500

    char* w = (char*)d_ws;
    // ---- zero region ----
    float* s_acc   = (float*)w;  w += (size_t)Nn * 128 * 4;
    int*   deg     = (int*)w;    w += (size_t)Nn * 4;
    int*   fill    = (int*)w;    w += (size_t)Nn * 4;
    float* stats1B = (float*)w;  w += (size_t)128 * 256 * 4;
    float* stats2  = (float*)w;  w += 512 * 4;
    size_t zbytes = (size_t)(w - (char*)d_ws);
    // ---- fully-overwritten region ----
    float* ss1    = (float*)w;  w += 256 * 4;
    float* ss2    = (float*)w;  w += 512 * 4;
    ushort* W1t   = (ushort*)w; w += 128 * 192 * 2;
    ushort* W2t   = (ushort*)w; w += 256 * 256 * 2;
    ushort* Wlt   = (ushort*)w; w += 128 * 256 * 2;
    ushort* xb    = (ushort*)w; w += (size_t)Nn * 128 * 2;
    ushort* h2    = (ushort*)w; w += (size_t)Nn * 256 * 2;
    int*   base   = (int*)w;    w += (size_t)Nn * 4;
    int*   bsum   = (int*)w;    w += (size_t)NB * 4;
    int*   bbase  = (int*)w;    w += (size_t)NB * 4;
    int*   perm   = (int*)w;    w += (size_t)E * 4;
    int*   srcs_s = (int*)w;    w += (size_t)E * 4;
    int*   dsts_s = (int*)w;    w += (size_t)E * 4;
    ushort* xab   = (ushort*)w; w += (size_t)Nn * 128 * 2;
    float* xa     = (float*)w;  w += (size_t)Nn * 128 * 4;
    size_t need_fb = (size_t)(w - (char*)d_ws);
    ushort* h_s   = (ushort*)w; w += (size_t)E * 128 * 2;
    size_t need_main = (size_t)(w - (char*)d_ws);
    (void)n_in; (void)out_size;

    const bool main_path = (ws_size >= need_main);

    hipMemsetAsync(d_ws, 0, zbytes, stream);

    const int GS = 2048;

    k_prep_wp<<<(192 * 128 + 255) / 256, 256, 0, stream>>>(W1, W1t, 192, 128);
    k_prep_wp<<<(256 * 256 + 255) / 256, 256, 0, stream>>>(W2, W2t, 256, 256);
    k_prep_wp<<<(256 * 128 + 255) / 256, 256, 0, stream>>>(Wl, Wlt, 256, 128);
    k_prep_x<<<GS, 256, 0, stream>>>(x, xb, Nn * 128 / 4);

    // sort edges by dst
    k_hist<<<GS, 256, 0, stream>>>(eidx + E, deg, E);
    k_bsum<<<NB, 256, 0, stream>>>(deg, bsum, Nn);
    k_bscan<<<1, 256, 0, stream>>>(bsum, bbase, NB);
    k_base<<<NB, 256, 0, stream>>>(deg, bbase, base, Nn);
    k_scatter<<<GS, 256, 0, stream>>>(eidx, base, fill, perm,
                                      main_path ? srcs_s : nullptr,
                                      main_path ? dsts_s : nullptr, E);

    if (main_path) {
        k_xa<true><<<(Nn + 127) / 128, 256, 0, stream>>>(xb, W1t, (void*)xab, Nn);
        k_edgeA<<<GS, 256, 0, stream>>>(ea, perm, srcs_s, W1t, xab, stats1B, h_s, E, NT);
        k_fin1<<<1, 128, 0, stream>>>(stats1B, g1, be1, ss1, 1.0f / (float)E);
        k_edgeB<<<GS, 256, 0, stream>>>(h_s, dsts_s, ss1, s_acc, E, NT);
    } else {
        (void)need_fb;
        k_xa<false><<<(Nn + 127) / 128, 256, 0, stream>>>(xb, W1t, (void*)xa, Nn);
        k_edge1<<<GS, 256, 0, stream>>>(ea, eidx, W1t, xa, stats1B, E, NT);
        k_fin1<<<1, 128, 0, stream>>>(stats1B, g1, be1, ss1, 1.0f / (float)E);
        k_edge2<<<GS, 256, 0, stream>>>(ea, eidx, perm, W1t, xa, ss1, s_acc, E, NT);
    }

    dim3 grid2((Nn + 127) / 128, 2);
    k_gemm2<<<grid2, 256, 0, stream>>>(xb, s_acc, deg, W2t, stats2, h2, Nn);
    k_fin<<<1, 256, 0, stream>>>(stats2, g2, be2, ss2, 256, 1.0f / (float)Nn);
    k_gemm3<<<(Nn + 127) / 128, 256, 0, stream>>>(h2, ss2, Wlt, bl, (float*)d_out, Nn);
}